// Round 11
// baseline (566.544 us; speedup 1.0000x reference)
//
#include <hip/hip_runtime.h>
#include <cstdint>
#include <cstddef>

typedef unsigned int u32;
typedef unsigned short u16;
typedef float  f32x4 __attribute__((ext_vector_type(4)));
typedef short  s16x8 __attribute__((ext_vector_type(8)));
typedef unsigned short u16x4 __attribute__((ext_vector_type(4)));

typedef const __attribute__((address_space(1))) u32 gbl_u32;
typedef __attribute__((address_space(3))) u32 lds_u32;

__device__ __forceinline__ u16 f2bf(float f) {          // RNE f32->bf16 (finite inputs)
    u32 u = __builtin_bit_cast(u32, f);
    u = (u + 0x7FFFu + ((u >> 16) & 1u)) >> 16;
    return (u16)u;
}

// ---------------- fused elementwise f32 -> bf16 convert (Q,K,V in one launch) ------------
__global__ void k_cvt3(const float* __restrict__ s0, const float* __restrict__ s1,
                       const float* __restrict__ s2, u16* __restrict__ d) {
    int i = blockIdx.x * 256 + threadIdx.x;              // float4 id, 3*524288 total
    int seg = i >> 19, off = i & 524287;
    const float* s = (seg == 0) ? s0 : (seg == 1) ? s1 : s2;
    float4 v = ((const float4*)s)[off];
    u16x4 o = { f2bf(v.x), f2bf(v.y), f2bf(v.z), f2bf(v.w) };
    *(u16x4*)(d + (size_t)i * 4) = o;
}

// ------- batched transpose+convert: W[bz] f32 [R][C] -> bf16 [C][R] (R=512, C=4096) ------
__global__ void k_tcvt3(const float* __restrict__ s0, const float* __restrict__ s1,
                        const float* __restrict__ s2, u16* __restrict__ d) {
    __shared__ float t[32][33];
    const int R = 512, C = 4096;
    int bx = blockIdx.x, by = blockIdx.y, bz = blockIdx.z;
    const float* s = (bz == 0) ? s0 : (bz == 1) ? s1 : s2;
    u16* dd = d + (size_t)bz * 2097152;
    int tx = threadIdx.x, ty = threadIdx.y;
    #pragma unroll
    for (int j = ty; j < 32; j += 8)
        t[j][tx] = s[(size_t)(by * 32 + j) * C + bx * 32 + tx];
    __syncthreads();
    #pragma unroll
    for (int j = ty; j < 32; j += 8)
        dd[(size_t)(bx * 32 + j) * R + by * 32 + tx] = f2bf(t[tx][j]);
}

// ---------------- transpose + convert: src f32 [R][C] -> dst bf16 [C][R] ----------------
__global__ void k_tcvt(const float* __restrict__ s, u16* __restrict__ d, int R, int C) {
    __shared__ float t[32][33];
    int bx = blockIdx.x, by = blockIdx.y;
    int tx = threadIdx.x, ty = threadIdx.y;
    #pragma unroll
    for (int j = ty; j < 32; j += 8)
        t[j][tx] = s[(size_t)(by * 32 + j) * C + bx * 32 + tx];
    __syncthreads();
    #pragma unroll
    for (int j = ty; j < 32; j += 8)
        d[(size_t)(bx * 32 + j) * R + by * 32 + tx] = f2bf(t[tx][j]);
}

// final reduce: out = bias + sum over splitk partials   (2097152 f32 = 524288 float4)
__global__ void k_reduce(const float* __restrict__ part, const float* __restrict__ bias,
                         float* __restrict__ out, int splitk) {
    int i = blockIdx.x * 256 + threadIdx.x;          // float4 id
    float4 s = ((const float4*)bias)[i & 127];
    for (int j = 0; j < splitk; ++j) {
        float4 p = ((const float4*)part)[(size_t)j * 524288 + i];
        s.x += p.x; s.y += p.y; s.z += p.z; s.w += p.w;
    }
    ((float4*)out)[i] = s;
}

// ================= 256x128xK bf16 GEMM, B given transposed [N][K] ==================
// 8 waves (4M x 2N), BK=64, single-buffered 48 KiB LDS, plain __syncthreads loop.
// MODE 0: QKV projections (bz=mat)   MODE 3: split-K partials of Oattn@Wo
template<int MODE>
__global__ __launch_bounds__(512, 4) void k_gemm(
    const u16* __restrict__ Abase, const u16* __restrict__ Bbase,
    u16* __restrict__ out0, u16* __restrict__ out1, u16* __restrict__ out2,
    float* __restrict__ outf,
    const float* __restrict__ bias0, const float* __restrict__ bias1,
    const float* __restrict__ bias2,
    int ktiles)
{
    constexpr int LDA = (MODE == 3) ? 4096 : 512;
    constexpr int LDB = (MODE == 3) ? 4096 : 512;

    __shared__ u16 lsA[256][64];       // 32 KiB
    __shared__ u16 lsB[128][64];       // 16 KiB

    const int tid = threadIdx.x;
    const int bx = blockIdx.x, by = blockIdx.y, bz = blockIdx.z;

    const u16* A; const u16* Bt;
    if constexpr (MODE == 0) {
        A  = Abase + (size_t)bz * 2097152 + (size_t)by * 256 * 512;
        Bt = Bbase + (size_t)bz * 2097152 + (size_t)bx * 128 * 512;
    } else {
        A  = Abase + (size_t)by * 256 * 4096 + (size_t)bz * (ktiles * 64);
        Bt = Bbase + (size_t)bx * 128 * 4096 + (size_t)bz * (ktiles * 64);
    }

    const int l  = tid & 63, w = tid >> 6;
    const int wm = (w >> 1) * 64, wn = (w & 1) * 64;         // 4 M-waves x 2 N-waves
    const int lg = l >> 4, lr = l & 15;
    const int swz = (lr & 7) << 4;

    f32x4 acc[4][4];
    #pragma unroll
    for (int m = 0; m < 4; ++m)
        #pragma unroll
        for (int n = 0; n < 4; ++n)
            #pragma unroll
            for (int r = 0; r < 4; ++r) acc[m][n][r] = 0.f;

    for (int t = 0; t < ktiles; ++t) {
        const int koff = t * 64;
        #pragma unroll
        for (int i = 0; i < 4; ++i) {
            const int a   = (i * 512 + tid) * 16;
            const int row = a >> 7;                          // 0..255
            const int cb  = (a & 127) ^ ((row & 7) << 4);
            const u16* ga = A + (size_t)row * LDA + koff + (cb >> 1);
            lds_u32* la = (lds_u32*)((char*)&lsA[0][0] + i * 8192 + (w << 10));
            __builtin_amdgcn_global_load_lds((gbl_u32*)ga, la, 16, 0, 0);
        }
        #pragma unroll
        for (int i = 0; i < 2; ++i) {
            const int a   = (i * 512 + tid) * 16;
            const int row = a >> 7;                          // 0..127
            const int cb  = (a & 127) ^ ((row & 7) << 4);
            const u16* gb = Bt + (size_t)row * LDB + koff + (cb >> 1);
            lds_u32* lb = (lds_u32*)((char*)&lsB[0][0] + i * 8192 + (w << 10));
            __builtin_amdgcn_global_load_lds((gbl_u32*)gb, lb, 16, 0, 0);
        }
        __syncthreads();

        #pragma unroll
        for (int ks = 0; ks < 2; ++ks) {
            s16x8 av[4], bv[4];
            #pragma unroll
            for (int m = 0; m < 4; ++m) {
                const int row = wm + m * 16 + lr;
                av[m] = *(const s16x8*)((const char*)&lsA[0][0] + row * 128 + ((ks * 64 + lg * 16) ^ swz));
            }
            #pragma unroll
            for (int n = 0; n < 4; ++n) {
                const int row = wn + n * 16 + lr;
                bv[n] = *(const s16x8*)((const char*)&lsB[0][0] + row * 128 + ((ks * 64 + lg * 16) ^ swz));
            }
            #pragma unroll
            for (int m = 0; m < 4; ++m)
                #pragma unroll
                for (int n = 0; n < 4; ++n)
                    acc[m][n] = __builtin_amdgcn_mfma_f32_16x16x32_bf16(av[m], bv[n], acc[m][n], 0, 0, 0);
        }
        __syncthreads();
    }

    // epilogue: C/D col = lr, row = lg*4 + r  [m89 verified]
    if constexpr (MODE == 0) {
        const float* bias = (bz == 0) ? bias0 : ((bz == 1) ? bias1 : bias2);
        #pragma unroll
        for (int m = 0; m < 4; ++m)
        #pragma unroll
        for (int n = 0; n < 4; ++n)
        #pragma unroll
        for (int r = 0; r < 4; ++r) {
            const int grow = by * 256 + wm + m * 16 + lg * 4 + r;   // b*2048+s
            const int gcol = bx * 128 + wn + n * 16 + lr;           // h*512+d
            const u16 o = f2bf(acc[m][n][r] + bias[gcol]);
            const int bb = grow >> 11, ss = grow & 2047;
            const int hh = gcol >> 9,  dd = gcol & 511;
            if (bz == 0)      out0[(((size_t)(bb * 8 + hh) * 2048 + ss) << 9)  + dd] = o;
            else if (bz == 1) out1[(((size_t)(bb * 8 + hh) * 2048 + ss) << 9)  + dd] = o;
            else              out2[(((size_t)(bb * 8 + hh) * 512  + dd) << 11) + ss] = o; // v^T
        }
    } else {
        #pragma unroll
        for (int m = 0; m < 4; ++m)
        #pragma unroll
        for (int n = 0; n < 4; ++n)
        #pragma unroll
        for (int r = 0; r < 4; ++r) {
            const int grow = by * 256 + wm + m * 16 + lg * 4 + r;       // 0..4095
            const int gcol = bx * 128 + wn + n * 16 + lr;               // 0..511
            outf[(size_t)bz * 2097152 + (size_t)grow * 512 + gcol] = acc[m][n][r];
        }
    }
}

// ================= fused attention: O = softmax(QK^T*scale) V  =================
// Per block: one (bh, 64-row q-tile). 256 threads / 4 waves; 2 blocks/CU.
// No max-subtraction needed (|s*scale| <= ~2, session-verified): P = exp(s*scale),
// rowsum accumulated in LDS via ds atomics, single divide at the end -> no rescaling.
// S-phase: S(64x128) = Q(64x512)K^T, BK=64, waves split kv (4x32).
// P -> swizzled LDS (16 KB). PV-phase: O(64x512) += P*V, kv slices of 32,
// waves split d (4x128). acc_o = 128 VGPR/lane, lives across all 16 kv-tiles.
__global__ __launch_bounds__(256, 2) void k_attn(
    const u16* __restrict__ qproj, const u16* __restrict__ kproj,
    const u16* __restrict__ vT, u16* __restrict__ Oattn)
{
    __shared__ char stage[32768];      // S-phase: Q 8K @0 + K 16K @8192; PV: V 32K @0
    __shared__ u16  Pl[8192];          // P tile [64][128] bf16, 256B rows, XOR-swizzled
    __shared__ float rs[64];           // running row sums

    const int tid = threadIdx.x;
    const int qt = blockIdx.x, bh = blockIdx.y;
    const int l = tid & 63, w = tid >> 6;
    const int lg = l >> 4, lr = l & 15;
    const int swz = (lr & 7) << 4;

    const u16* Qb = qproj + (size_t)bh * 1048576 + (size_t)qt * 64 * 512;
    const u16* Kb = kproj + (size_t)bh * 1048576;
    const u16* Vb = vT    + (size_t)bh * 1048576;

    if (tid < 64) rs[tid] = 0.f;

    const int wn = w * 32;             // S-phase kv-quarter
    const int wd = w * 128;            // PV-phase d-quarter

    f32x4 acc_o[4][8];
    #pragma unroll
    for (int m = 0; m < 4; ++m)
        #pragma unroll
        for (int n = 0; n < 8; ++n)
            #pragma unroll
            for (int r = 0; r < 4; ++r) acc_o[m][n][r] = 0.f;

    __syncthreads();                   // rs zero visible

    for (int t = 0; t < 16; ++t) {
        const int kv0 = t * 128;

        // ---- S = Q K^T  (K=512, 8 steps of BK=64) ----
        f32x4 acc_s[4][2];
        #pragma unroll
        for (int m = 0; m < 4; ++m)
            #pragma unroll
            for (int n = 0; n < 2; ++n)
                #pragma unroll
                for (int r = 0; r < 4; ++r) acc_s[m][n][r] = 0.f;

        for (int k8 = 0; k8 < 8; ++k8) {
            const int koff = k8 * 64;
            #pragma unroll
            for (int i = 0; i < 2; ++i) {              // Q [64][64] -> 8 KB
                const int a = (i * 256 + tid) * 16;
                const int row = a >> 7;
                const int cb = (a & 127) ^ ((row & 7) << 4);
                const u16* g = Qb + (size_t)row * 512 + koff + (cb >> 1);
                lds_u32* dp = (lds_u32*)(stage + i * 4096 + (w << 10));
                __builtin_amdgcn_global_load_lds((gbl_u32*)g, dp, 16, 0, 0);
            }
            #pragma unroll
            for (int i = 0; i < 4; ++i) {              // K [128][64] -> 16 KB @8192
                const int a = (i * 256 + tid) * 16;
                const int row = a >> 7;
                const int cb = (a & 127) ^ ((row & 7) << 4);
                const u16* g = Kb + (size_t)(kv0 + row) * 512 + koff + (cb >> 1);
                lds_u32* dp = (lds_u32*)(stage + 8192 + i * 4096 + (w << 10));
                __builtin_amdgcn_global_load_lds((gbl_u32*)g, dp, 16, 0, 0);
            }
            __syncthreads();
            #pragma unroll
            for (int ks = 0; ks < 2; ++ks) {
                s16x8 av[4], bv[2];
                #pragma unroll
                for (int m = 0; m < 4; ++m) {
                    const int row = m * 16 + lr;
                    av[m] = *(const s16x8*)(stage + row * 128 + ((ks * 64 + lg * 16) ^ swz));
                }
                #pragma unroll
                for (int n = 0; n < 2; ++n) {
                    const int row = wn + n * 16 + lr;
                    bv[n] = *(const s16x8*)(stage + 8192 + row * 128 + ((ks * 64 + lg * 16) ^ swz));
                }
                #pragma unroll
                for (int m = 0; m < 4; ++m)
                    #pragma unroll
                    for (int n = 0; n < 2; ++n)
                        acc_s[m][n] = __builtin_amdgcn_mfma_f32_16x16x32_bf16(av[m], bv[n], acc_s[m][n], 0, 0, 0);
            }
            __syncthreads();
        }

        // ---- P = exp(S*scale) -> Pl (swizzled); rs += row partials ----
        #pragma unroll
        for (int m = 0; m < 4; ++m)
        #pragma unroll
        for (int r = 0; r < 4; ++r) {
            const int q = m * 16 + lg * 4 + r;
            float ps = 0.f;
            #pragma unroll
            for (int n = 0; n < 2; ++n) {
                const int kvl = wn + n * 16 + lr;
                float p = __expf(acc_s[m][n][r] * 0.04419417382415922f);  // 1/sqrt(512)
                ps += p;
                const int byt = q * 256 + ((2 * kvl) ^ ((q & 7) << 4));
                *(u16*)((char*)Pl + byt) = f2bf(p);
            }
            ps += __shfl_xor(ps, 1, 64); ps += __shfl_xor(ps, 2, 64);
            ps += __shfl_xor(ps, 4, 64); ps += __shfl_xor(ps, 8, 64);
            if (lr == 0) atomicAdd(&rs[q], ps);
        }
        __syncthreads();               // P visible; stage region free for V

        // ---- O += P V  (kv=128, 4 slices of 32) ----
        #pragma unroll
        for (int ks = 0; ks < 4; ++ks) {
            #pragma unroll
            for (int i = 0; i < 8; ++i) {              // V slice [512][32] -> 32 KB
                const int a = (i * 256 + tid) * 16;
                const int row = a >> 6;                // 0..511  (d)
                const int cb = (a & 63) ^ ((((row >> 1) & 3)) << 4);
                const u16* g = Vb + (size_t)row * 2048 + kv0 + ks * 32 + (cb >> 1);
                lds_u32* dp = (lds_u32*)(stage + i * 4096 + (w << 10));
                __builtin_amdgcn_global_load_lds((gbl_u32*)g, dp, 16, 0, 0);
            }
            __syncthreads();
            s16x8 av[4], bv[8];
            #pragma unroll
            for (int m = 0; m < 4; ++m) {              // A = P rows (q)
                const int q = m * 16 + lr;
                av[m] = *(const s16x8*)((char*)Pl + q * 256 + ((ks * 64 + lg * 16) ^ ((q & 7) << 4)));
            }
            #pragma unroll
            for (int n = 0; n < 8; ++n) {              // B = V^T rows (d)
                const int row = wd + n * 16 + lr;
                bv[n] = *(const s16x8*)(stage + row * 64 + ((lg * 16) ^ ((((row >> 1) & 3)) << 4)));
            }
            #pragma unroll
            for (int m = 0; m < 4; ++m)
                #pragma unroll
                for (int n = 0; n < 8; ++n)
                    acc_o[m][n] = __builtin_amdgcn_mfma_f32_16x16x32_bf16(av[m], bv[n], acc_o[m][n], 0, 0, 0);
            __syncthreads();
        }
    }

    // ---- final: O /= rs; store to Oattn [B*S][4096] ----
    const int bb = bh >> 3, hh = bh & 7;
    #pragma unroll
    for (int m = 0; m < 4; ++m)
    #pragma unroll
    for (int r = 0; r < 4; ++r) {
        const int q = m * 16 + lg * 4 + r;
        const float ri = 1.0f / rs[q];
        const int grow = bb * 2048 + qt * 64 + q;
        #pragma unroll
        for (int n = 0; n < 8; ++n) {
            const int d = wd + n * 16 + lr;
            Oattn[((size_t)grow << 12) + hh * 512 + d] = f2bf(acc_o[m][n][r] * ri);
        }
    }
}

extern "C" void kernel_launch(void* const* d_in, const int* in_sizes, int n_in,
                              void* d_out, int out_size, void* d_ws, size_t ws_size,
                              hipStream_t stream) {
    const float* Q  = (const float*)d_in[0];
    const float* K  = (const float*)d_in[1];
    const float* V  = (const float*)d_in[2];
    const float* bq = (const float*)d_in[4];
    const float* bk = (const float*)d_in[6];
    const float* bv = (const float*)d_in[8];
    const float* bo = (const float*)d_in[10];
    const float* Wq = (const float*)d_in[3];
    const float* Wk = (const float*)d_in[5];
    const float* Wv = (const float*)d_in[7];
    const float* Wo = (const float*)d_in[9];
    float* out = (float*)d_out;

    char* ws = (char*)d_ws;
    u16*   qkvbf = (u16*)  (ws + 0);            // [3][4096][512] bf16
    u16*   Wt    = (u16*)  (ws + 12582912);     // Wq^T,Wk^T,Wv^T [3][4096][512]
    u16*   WoT   = (u16*)  (ws + 25165824);     // Wo^T [512][4096]
    u16*   qproj = (u16*)  (ws + 29491200);     // [B,H,S,512]
    u16*   kproj = (u16*)  (ws + 63045632);     // [B,H,S,512]
    u16*   vT    = (u16*)  (ws + 96600064);     // [B,H,512,S]
    u16*   Oattn = (u16*)  (ws + 130154496);    // [B*S][4096]
    float* part  = (float*)(ws + 163708928);    // [splitk][4096][512] f32

    size_t avail = (ws_size > (size_t)163708928) ? ws_size - (size_t)163708928 : 0;
    int maxp = (int)(avail / 8388608);
    int splitk = (maxp >= 8) ? 8 : (maxp >= 4) ? 4 : (maxp >= 2) ? 2 : 1;

    // input converts (fused launches)
    k_cvt3<<<6144, 256, 0, stream>>>(Q, K, V, qkvbf);
    dim3 tb(32, 8);
    k_tcvt3<<<dim3(128, 16, 3), tb, 0, stream>>>(Wq, Wk, Wv, Wt);
    k_tcvt<<<dim3(16, 128), tb, 0, stream>>>(Wo, WoT, 4096, 512);

    // fused QKV projections (+bias): q,k -> [B,H,S,D], v -> [B,H,D,S]
    k_gemm<0><<<dim3(32, 16, 3), 512, 0, stream>>>(qkvbf, Wt, qproj, kproj, vT, nullptr,
                                                   bq, bk, bv, 8);

    // fused attention: O = softmax(QK^T/sqrt(512)) V  -> Oattn
    k_attn<<<dim3(32, 16), 256, 0, stream>>>(qproj, kproj, vT, Oattn);

    // final projection: split-K partials + reduce(+bias) -> f32 out
    k_gemm<3><<<dim3(4, 16, splitk), 512, 0, stream>>>(Oattn, WoT, nullptr, nullptr, nullptr,
                                                       part, nullptr, nullptr, nullptr,
                                                       64 / splitk);
    k_reduce<<<2048, 256, 0, stream>>>(part, bo, out, splitk);
}

// Round 12
// 429.098 us; speedup vs baseline: 1.3203x; 1.3203x over previous
//
#include <hip/hip_runtime.h>
#include <cstdint>
#include <cstddef>

typedef unsigned int u32;
typedef unsigned short u16;
typedef float  f32x4 __attribute__((ext_vector_type(4)));
typedef short  s16x8 __attribute__((ext_vector_type(8)));
typedef unsigned short u16x4 __attribute__((ext_vector_type(4)));

typedef const __attribute__((address_space(1))) u32 gbl_u32;
typedef __attribute__((address_space(3))) u32 lds_u32;

__device__ __forceinline__ u16 f2bf(float f) {          // RNE f32->bf16 (finite inputs)
    u32 u = __builtin_bit_cast(u32, f);
    u = (u + 0x7FFFu + ((u >> 16) & 1u)) >> 16;
    return (u16)u;
}

// ---------------- fused elementwise f32 -> bf16 convert (Q,K,V in one launch) ------------
__global__ void k_cvt3(const float* __restrict__ s0, const float* __restrict__ s1,
                       const float* __restrict__ s2, u16* __restrict__ d) {
    int i = blockIdx.x * 256 + threadIdx.x;              // float4 id, 3*524288 total
    int seg = i >> 19, off = i & 524287;
    const float* s = (seg == 0) ? s0 : (seg == 1) ? s1 : s2;
    float4 v = ((const float4*)s)[off];
    u16x4 o = { f2bf(v.x), f2bf(v.y), f2bf(v.z), f2bf(v.w) };
    *(u16x4*)(d + (size_t)i * 4) = o;
}

// ------- batched transpose+convert: W[bz] f32 [R][C] -> bf16 [C][R] (R=512, C=4096) ------
__global__ void k_tcvt3(const float* __restrict__ s0, const float* __restrict__ s1,
                        const float* __restrict__ s2, u16* __restrict__ d) {
    __shared__ float t[32][33];
    const int R = 512, C = 4096;
    int bx = blockIdx.x, by = blockIdx.y, bz = blockIdx.z;
    const float* s = (bz == 0) ? s0 : (bz == 1) ? s1 : s2;
    u16* dd = d + (size_t)bz * 2097152;
    int tx = threadIdx.x, ty = threadIdx.y;
    #pragma unroll
    for (int j = ty; j < 32; j += 8)
        t[j][tx] = s[(size_t)(by * 32 + j) * C + bx * 32 + tx];
    __syncthreads();
    #pragma unroll
    for (int j = ty; j < 32; j += 8)
        dd[(size_t)(bx * 32 + j) * R + by * 32 + tx] = f2bf(t[tx][j]);
}

// ---------------- transpose + convert: src f32 [R][C] -> dst bf16 [C][R] ----------------
__global__ void k_tcvt(const float* __restrict__ s, u16* __restrict__ d, int R, int C) {
    __shared__ float t[32][33];
    int bx = blockIdx.x, by = blockIdx.y;
    int tx = threadIdx.x, ty = threadIdx.y;
    #pragma unroll
    for (int j = ty; j < 32; j += 8)
        t[j][tx] = s[(size_t)(by * 32 + j) * C + bx * 32 + tx];
    __syncthreads();
    #pragma unroll
    for (int j = ty; j < 32; j += 8)
        d[(size_t)(bx * 32 + j) * R + by * 32 + tx] = f2bf(t[tx][j]);
}

__global__ void k_zero(float* __restrict__ p, int n) {
    int i = blockIdx.x * 256 + threadIdx.x;
    if (i < n) p[i] = 0.f;
}

// final reduce: out = bias + sum over splitk partials   (2097152 f32 = 524288 float4)
__global__ void k_reduce(const float* __restrict__ part, const float* __restrict__ bias,
                         float* __restrict__ out, int splitk) {
    int i = blockIdx.x * 256 + threadIdx.x;          // float4 id
    float4 s = ((const float4*)bias)[i & 127];
    for (int j = 0; j < splitk; ++j) {
        float4 p = ((const float4*)part)[(size_t)j * 524288 + i];
        s.x += p.x; s.y += p.y; s.z += p.z; s.w += p.w;
    }
    ((float4*)out)[i] = s;
}

// ================= 256x256xK bf16 GEMM, B given transposed [N][K] ==================
// High-AI / CU-feed-optimized: 8 waves (2M x 4N, each wave 128x64 out), BK=64,
// SINGLE-buffered 64 KiB LDS, plain __syncthreads 2-barrier loop; 2 blocks/CU
// (launch_bounds(512,2): ~210 regs <= 256). AI = 256 FLOP per staged byte (4x the
// 128^2 tile) -> CU L2-feed ceiling rises 22% -> ~55% MfmaUtil.
// XOR-swizzled LDS (0-conflict verified), global_load_lds width 16.
// MODE 0: QKV projections (bz=mat)  MODE 1: P=exp(qk^T*scale)+rowsum-atomic
// MODE 2: O=(P v)/rowsum            MODE 3: split-K partials of Oattn@Wo
template<int MODE>
__global__ __launch_bounds__(512, 2) void k_gemm(
    const u16* __restrict__ Abase, const u16* __restrict__ Bbase,
    u16* __restrict__ out0, u16* __restrict__ out1, u16* __restrict__ out2,
    float* __restrict__ outf,
    const float* __restrict__ bias0, const float* __restrict__ bias1,
    const float* __restrict__ bias2,
    float* __restrict__ rsum, int bh_base, int ktiles)
{
    constexpr int LDA = (MODE == 2) ? 2048 : (MODE == 3) ? 4096 : 512;
    constexpr int LDB = (MODE == 2) ? 2048 : (MODE == 3) ? 4096 : 512;

    __shared__ u16 lsA[256][64];       // 32 KiB
    __shared__ u16 lsB[256][64];       // 32 KiB

    const int tid = threadIdx.x;
    const int bx = blockIdx.x, by = blockIdx.y, bz = blockIdx.z;

    const u16* A; const u16* Bt;
    if constexpr (MODE == 0) {
        A  = Abase + (size_t)bz * 2097152 + (size_t)by * 256 * 512;
        Bt = Bbase + (size_t)bz * 2097152 + (size_t)bx * 256 * 512;
    } else if constexpr (MODE == 1) {
        int bh = bh_base + bz;
        A  = Abase + (size_t)bh * 1048576 + (size_t)by * 256 * 512;
        Bt = Bbase + (size_t)bh * 1048576 + (size_t)bx * 256 * 512;
    } else if constexpr (MODE == 2) {
        int bh = bh_base + bz;
        A  = Abase + (size_t)bz * 4194304 + (size_t)by * 256 * 2048;
        Bt = Bbase + (size_t)bh * 1048576 + (size_t)bx * 256 * 2048;
    } else {
        A  = Abase + (size_t)by * 256 * 4096 + (size_t)bz * (ktiles * 64);
        Bt = Bbase + (size_t)bx * 256 * 4096 + (size_t)bz * (ktiles * 64);
    }

    const int l  = tid & 63, w = tid >> 6;
    const int wm = (w >> 2) * 128, wn = (w & 3) * 64;        // 2 M-waves x 4 N-waves
    const int lg = l >> 4, lr = l & 15;
    const int swz = (lr & 7) << 4;

    f32x4 acc[8][4];
    #pragma unroll
    for (int m = 0; m < 8; ++m)
        #pragma unroll
        for (int n = 0; n < 4; ++n)
            #pragma unroll
            for (int r = 0; r < 4; ++r) acc[m][n][r] = 0.f;

    for (int t = 0; t < ktiles; ++t) {
        const int koff = t * 64;
        // ---- stage tile t: A 32 KB + B 32 KB (4 rounds each); linear LDS dest,
        //      inverse-swizzled global source ----
        #pragma unroll
        for (int i = 0; i < 4; ++i) {
            const int a   = (i * 512 + tid) * 16;            // linear byte in 32KB region
            const int row = a >> 7;                          // 0..255
            const int cb  = (a & 127) ^ ((row & 7) << 4);    // logical byte-in-row
            const u16* ga = A  + (size_t)row * LDA + koff + (cb >> 1);
            const u16* gb = Bt + (size_t)row * LDB + koff + (cb >> 1);
            lds_u32* la = (lds_u32*)((char*)&lsA[0][0] + i * 8192 + ((tid >> 6) << 10));
            lds_u32* lb = (lds_u32*)((char*)&lsB[0][0] + i * 8192 + ((tid >> 6) << 10));
            __builtin_amdgcn_global_load_lds((gbl_u32*)ga, la, 16, 0, 0);
            __builtin_amdgcn_global_load_lds((gbl_u32*)gb, lb, 16, 0, 0);
        }
        __syncthreads();                                     // drains vmcnt; tile resident

        // ---- compute: 2 k-slices x 32 MFMA per wave ----
        #pragma unroll
        for (int ks = 0; ks < 2; ++ks) {
            s16x8 av[8], bv[4];
            #pragma unroll
            for (int m = 0; m < 8; ++m) {
                const int row = wm + m * 16 + lr;
                av[m] = *(const s16x8*)((const char*)&lsA[0][0] + row * 128 + ((ks * 64 + lg * 16) ^ swz));
            }
            #pragma unroll
            for (int n = 0; n < 4; ++n) {
                const int row = wn + n * 16 + lr;
                bv[n] = *(const s16x8*)((const char*)&lsB[0][0] + row * 128 + ((ks * 64 + lg * 16) ^ swz));
            }
            #pragma unroll
            for (int m = 0; m < 8; ++m)
                #pragma unroll
                for (int n = 0; n < 4; ++n)
                    acc[m][n] = __builtin_amdgcn_mfma_f32_16x16x32_bf16(av[m], bv[n], acc[m][n], 0, 0, 0);
        }
        __syncthreads();                                     // all reads done before next stage
    }

    // ---------------- epilogue: C/D col = lr, row = lg*4 + r  [m89 verified] ----------------
    if constexpr (MODE == 0) {
        const float* bias = (bz == 0) ? bias0 : ((bz == 1) ? bias1 : bias2);
        #pragma unroll
        for (int m = 0; m < 8; ++m)
        #pragma unroll
        for (int n = 0; n < 4; ++n)
        #pragma unroll
        for (int r = 0; r < 4; ++r) {
            const int grow = by * 256 + wm + m * 16 + lg * 4 + r;   // b*2048+s
            const int gcol = bx * 256 + wn + n * 16 + lr;           // h*512+d
            const u16 o = f2bf(acc[m][n][r] + bias[gcol]);
            const int bb = grow >> 11, ss = grow & 2047;
            const int hh = gcol >> 9,  dd = gcol & 511;
            if (bz == 0)      out0[(((size_t)(bb * 8 + hh) * 2048 + ss) << 9)  + dd] = o;
            else if (bz == 1) out1[(((size_t)(bb * 8 + hh) * 2048 + ss) << 9)  + dd] = o;
            else              out2[(((size_t)(bb * 8 + hh) * 512  + dd) << 11) + ss] = o; // v^T
        }
    } else if constexpr (MODE == 1) {
        const int bh = bh_base + bz;
        u16* Pp = out0 + (size_t)bz * 4194304;
        #pragma unroll
        for (int m = 0; m < 8; ++m)
        #pragma unroll
        for (int r = 0; r < 4; ++r) {
            const int grow = by * 256 + wm + m * 16 + lg * 4 + r;
            float rs = 0.f;
            #pragma unroll
            for (int n = 0; n < 4; ++n) {
                const int gcol = bx * 256 + wn + n * 16 + lr;
                float p = __expf(acc[m][n][r] * 0.04419417382415922f);  // 1/sqrt(512)
                rs += p;
                Pp[((size_t)grow << 11) + gcol] = f2bf(p);
            }
            #pragma unroll
            for (int o = 1; o < 16; o <<= 1) rs += __shfl_xor(rs, o, 64);
            if (lr == 0) atomicAdd(&rsum[bh * 2048 + grow], rs);
        }
    } else if constexpr (MODE == 2) {
        const int bh = bh_base + bz;
        const int bb = bh >> 3, hh = bh & 7;
        #pragma unroll
        for (int m = 0; m < 8; ++m)
        #pragma unroll
        for (int r = 0; r < 4; ++r) {
            const int grow = by * 256 + wm + m * 16 + lg * 4 + r;
            const float ri = 1.0f / rsum[bh * 2048 + grow];
            #pragma unroll
            for (int n = 0; n < 4; ++n) {
                const int gcol = bx * 256 + wn + n * 16 + lr;           // 0..511
                out0[((size_t)(bb * 2048 + grow) << 12) + hh * 512 + gcol] = f2bf(acc[m][n][r] * ri);
            }
        }
    } else {
        #pragma unroll
        for (int m = 0; m < 8; ++m)
        #pragma unroll
        for (int n = 0; n < 4; ++n)
        #pragma unroll
        for (int r = 0; r < 4; ++r) {
            const int grow = by * 256 + wm + m * 16 + lg * 4 + r;       // 0..4095
            const int gcol = bx * 256 + wn + n * 16 + lr;               // 0..511
            outf[(size_t)bz * 2097152 + (size_t)grow * 512 + gcol] = acc[m][n][r];
        }
    }
}

extern "C" void kernel_launch(void* const* d_in, const int* in_sizes, int n_in,
                              void* d_out, int out_size, void* d_ws, size_t ws_size,
                              hipStream_t stream) {
    const float* Q  = (const float*)d_in[0];
    const float* K  = (const float*)d_in[1];
    const float* V  = (const float*)d_in[2];
    const float* bq = (const float*)d_in[4];
    const float* bk = (const float*)d_in[6];
    const float* bv = (const float*)d_in[8];
    const float* bo = (const float*)d_in[10];
    const float* Wq = (const float*)d_in[3];
    const float* Wk = (const float*)d_in[5];
    const float* Wv = (const float*)d_in[7];
    const float* Wo = (const float*)d_in[9];
    float* out = (float*)d_out;

    char* ws = (char*)d_ws;
    u16*   qkvbf = (u16*)  (ws + 0);            // [3][4096][512] bf16
    u16*   Wt    = (u16*)  (ws + 12582912);     // Wq^T,Wk^T,Wv^T [3][4096][512]
    u16*   WoT   = (u16*)  (ws + 25165824);     // Wo^T [512][4096]
    float* rsum  = (float*)(ws + 29360128);     // [16][2048]
    u16*   qproj = (u16*)  (ws + 29491200);     // [B,H,S,512]
    u16*   kproj = (u16*)  (ws + 63045632);     // [B,H,S,512]
    u16*   vT    = (u16*)  (ws + 96600064);     // [B,H,512,S]
    u16*   Oattn = (u16*)  (ws + 130154496);    // [B*S][4096]
    u16*   P     = (u16*)  (ws + 163708928);    // chunked [ch][2048][2048]
    float* part  = (float*)(ws + 163708928);    // reused after attn: [splitk][4096][512] f32

    size_t avail = (ws_size > (size_t)163708928) ? ws_size - (size_t)163708928 : 0;
    int hp = (int)(avail / 8388608);
    if (hp < 1)  hp = 1;
    if (hp > 16) hp = 16;
    int splitk = (hp >= 8) ? 8 : (hp >= 4) ? 4 : (hp >= 2) ? 2 : 1;

    // input converts (fused launches)
    k_cvt3<<<6144, 256, 0, stream>>>(Q, K, V, qkvbf);
    dim3 tb(32, 8);
    k_tcvt3<<<dim3(128, 16, 3), tb, 0, stream>>>(Wq, Wk, Wv, Wt);
    k_tcvt<<<dim3(16, 128), tb, 0, stream>>>(Wo, WoT, 4096, 512);
    k_zero<<<128, 256, 0, stream>>>(rsum, 32768);

    // fused QKV projections (+bias): q,k -> [B,H,S,D], v -> [B,H,D,S]
    k_gemm<0><<<dim3(16, 16, 3), 512, 0, stream>>>(qkvbf, Wt, qproj, kproj, vT, nullptr,
                                                   bq, bk, bv, nullptr, 0, 8);

    // attention: P = exp(qk^T*scale) with fused row-sums; O = P v / rowsum
    for (int h0 = 0; h0 < 16; h0 += hp) {
        int ch = (16 - h0 < hp) ? (16 - h0) : hp;
        k_gemm<1><<<dim3(8, 8, ch), 512, 0, stream>>>(qproj, kproj, P, nullptr, nullptr,
                                                      nullptr, nullptr, nullptr, nullptr,
                                                      rsum, h0, 8);
        k_gemm<2><<<dim3(2, 8, ch), 512, 0, stream>>>(P, vT, Oattn, nullptr, nullptr,
                                                      nullptr, nullptr, nullptr, nullptr,
                                                      rsum, h0, 32);
    }

    // final projection: split-K partials + reduce(+bias) -> f32 out
    k_gemm<3><<<dim3(2, 16, splitk), 512, 0, stream>>>(Oattn, WoT, nullptr, nullptr, nullptr,
                                                       part, nullptr, nullptr, nullptr,
                                                       nullptr, 0, 64 / splitk);
    k_reduce<<<2048, 256, 0, stream>>>(part, bo, out, splitk);
}

// Round 13
// 355.253 us; speedup vs baseline: 1.5948x; 1.2079x over previous
//
#include <hip/hip_runtime.h>
#include <cstdint>
#include <cstddef>

typedef unsigned int u32;
typedef unsigned short u16;
typedef unsigned char u8;
typedef float  f32x4 __attribute__((ext_vector_type(4)));
typedef short  s16x8 __attribute__((ext_vector_type(8)));
typedef unsigned short u16x4 __attribute__((ext_vector_type(4)));

typedef const __attribute__((address_space(1))) u32 gbl_u32;
typedef __attribute__((address_space(3))) u32 lds_u32;

__device__ __forceinline__ u16 f2bf(float f) {          // RNE f32->bf16 (finite inputs)
    u32 u = __builtin_bit_cast(u32, f);
    u = (u + 0x7FFFu + ((u >> 16) & 1u)) >> 16;
    return (u16)u;
}

// RNE f32 -> fp8 e4m3fn (|f| < 400, finite). Handles subnormals; flushes |f|<2^-9.
__device__ __forceinline__ u8 f2fp8(float f) {
    u32 u = __builtin_bit_cast(u32, f);
    u32 sgn = (u >> 24) & 0x80u;
    float af = __builtin_fabsf(f);
    if (af < 0.001953125f) return (u8)sgn;               // < 2^-9 -> 0
    int ex = (int)((u >> 23) & 0xffu) - 127;
    u32 mant = (u & 0x7fffffu) | 0x800000u;              // 1.m, 24 bits
    int shift = (ex >= -6) ? 20 : (14 - ex);
    u32 keep = mant >> shift;
    u32 rem  = mant & ((1u << shift) - 1u);
    u32 half = 1u << (shift - 1);
    keep += (rem > half || (rem == half && (keep & 1u))) ? 1u : 0u;
    u32 e8, m8;
    if (ex < -6) {                                       // subnormal (units 2^-9), keep in [1..8]
        if (keep >= 8u) { e8 = 1u; m8 = 0u; }
        else            { e8 = 0u; m8 = keep; }
    } else {
        if (keep >= 16u) { keep >>= 1; ex += 1; }
        e8 = (u32)(ex + 7); m8 = keep & 7u;
    }
    return (u8)(sgn | (e8 << 3) | m8);
}

// ---------------- fused elementwise f32 -> bf16 convert (Q,K,V in one launch) ------------
__global__ void k_cvt3(const float* __restrict__ s0, const float* __restrict__ s1,
                       const float* __restrict__ s2, u16* __restrict__ d) {
    int i = blockIdx.x * 256 + threadIdx.x;              // float4 id, 3*524288 total
    int seg = i >> 19, off = i & 524287;
    const float* s = (seg == 0) ? s0 : (seg == 1) ? s1 : s2;
    float4 v = ((const float4*)s)[off];
    u16x4 o = { f2bf(v.x), f2bf(v.y), f2bf(v.z), f2bf(v.w) };
    *(u16x4*)(d + (size_t)i * 4) = o;
}

// ------- batched transpose+convert: W[bz] f32 [R][C] -> bf16 [C][R] (R=512, C=4096) ------
__global__ void k_tcvt3(const float* __restrict__ s0, const float* __restrict__ s1,
                        const float* __restrict__ s2, u16* __restrict__ d) {
    __shared__ float t[32][33];
    const int R = 512, C = 4096;
    int bx = blockIdx.x, by = blockIdx.y, bz = blockIdx.z;
    const float* s = (bz == 0) ? s0 : (bz == 1) ? s1 : s2;
    u16* dd = d + (size_t)bz * 2097152;
    int tx = threadIdx.x, ty = threadIdx.y;
    #pragma unroll
    for (int j = ty; j < 32; j += 8)
        t[j][tx] = s[(size_t)(by * 32 + j) * C + bx * 32 + tx];
    __syncthreads();
    #pragma unroll
    for (int j = ty; j < 32; j += 8)
        dd[(size_t)(bx * 32 + j) * R + by * 32 + tx] = f2bf(t[tx][j]);
}

// ---------------- transpose + convert: src f32 [R][C] -> dst bf16 [C][R] ----------------
__global__ void k_tcvt(const float* __restrict__ s, u16* __restrict__ d, int R, int C) {
    __shared__ float t[32][33];
    int bx = blockIdx.x, by = blockIdx.y;
    int tx = threadIdx.x, ty = threadIdx.y;
    #pragma unroll
    for (int j = ty; j < 32; j += 8)
        t[j][tx] = s[(size_t)(by * 32 + j) * C + bx * 32 + tx];
    __syncthreads();
    #pragma unroll
    for (int j = ty; j < 32; j += 8)
        d[(size_t)(bx * 32 + j) * R + by * 32 + tx] = f2bf(t[tx][j]);
}

__global__ void k_zero(float* __restrict__ p, int n) {
    int i = blockIdx.x * 256 + threadIdx.x;
    if (i < n) p[i] = 0.f;
}

// final reduce: out = bias + sum over splitk partials   (2097152 f32 = 524288 float4)
__global__ void k_reduce(const float* __restrict__ part, const float* __restrict__ bias,
                         float* __restrict__ out, int splitk) {
    int i = blockIdx.x * 256 + threadIdx.x;          // float4 id
    float4 s = ((const float4*)bias)[i & 127];
    for (int j = 0; j < splitk; ++j) {
        float4 p = ((const float4*)part)[(size_t)j * 524288 + i];
        s.x += p.x; s.y += p.y; s.z += p.z; s.w += p.w;
    }
    ((float4*)out)[i] = s;
}

// ================= 128x128xK bf16 GEMM, B given transposed [N][K] ==================
// r7-verified structure: 4 waves (2x2), BK=64, single-buffered 32 KiB LDS, plain
// __syncthreads 2-barrier loop, 3 blocks/CU, 0-conflict XOR swizzle, width-16 loads.
// MODE 0: QKV projections (bz=mat; q,k out fp8, v out bf16 transposed)
// MODE 2: O=(P v)/rowsum            MODE 3: split-K partials of Oattn@Wo
template<int MODE>
__global__ __launch_bounds__(256, 3) void k_gemm(
    const u16* __restrict__ Abase, const u16* __restrict__ Bbase,
    u16* __restrict__ out0, u16* __restrict__ out1, u16* __restrict__ out2,
    float* __restrict__ outf,
    const float* __restrict__ bias0, const float* __restrict__ bias1,
    const float* __restrict__ bias2,
    float* __restrict__ rsum, int bh_base, int ktiles)
{
    constexpr int LDA = (MODE == 2) ? 2048 : (MODE == 3) ? 4096 : 512;
    constexpr int LDB = (MODE == 2) ? 2048 : (MODE == 3) ? 4096 : 512;

    __shared__ u16 lsA[128][64];       // 16 KiB
    __shared__ u16 lsB[128][64];       // 16 KiB

    const int tid = threadIdx.x;
    const int bx = blockIdx.x, by = blockIdx.y, bz = blockIdx.z;

    const u16* A; const u16* Bt;
    if constexpr (MODE == 0) {
        A  = Abase + (size_t)bz * 2097152 + (size_t)by * 128 * 512;
        Bt = Bbase + (size_t)bz * 2097152 + (size_t)bx * 128 * 512;
    } else if constexpr (MODE == 2) {
        int bh = bh_base + bz;
        A  = Abase + (size_t)bz * 4194304 + (size_t)by * 128 * 2048;
        Bt = Bbase + (size_t)bh * 1048576 + (size_t)bx * 128 * 2048;
    } else {
        A  = Abase + (size_t)by * 128 * 4096 + (size_t)bz * (ktiles * 64);
        Bt = Bbase + (size_t)bx * 128 * 4096 + (size_t)bz * (ktiles * 64);
    }

    const int l  = tid & 63, w = tid >> 6;
    const int wm = (w >> 1) * 64, wn = (w & 1) * 64;         // wave tile origin
    const int lg = l >> 4, lr = l & 15;
    const int swz = (lr & 7) << 4;

    f32x4 acc[4][4];
    #pragma unroll
    for (int m = 0; m < 4; ++m)
        #pragma unroll
        for (int n = 0; n < 4; ++n)
            #pragma unroll
            for (int r = 0; r < 4; ++r) acc[m][n][r] = 0.f;

    for (int t = 0; t < ktiles; ++t) {
        const int koff = t * 64;
        #pragma unroll
        for (int i = 0; i < 4; ++i) {
            const int a   = (i * 256 + tid) * 16;            // linear byte in 16KB region
            const int row = a >> 7;                          // 0..127
            const int cb  = (a & 127) ^ ((row & 7) << 4);    // logical byte-in-row
            const u16* ga = A  + (size_t)row * LDA + koff + (cb >> 1);
            const u16* gb = Bt + (size_t)row * LDB + koff + (cb >> 1);
            lds_u32* la = (lds_u32*)((char*)&lsA[0][0] + i * 4096 + (w << 10));
            lds_u32* lb = (lds_u32*)((char*)&lsB[0][0] + i * 4096 + (w << 10));
            __builtin_amdgcn_global_load_lds((gbl_u32*)ga, la, 16, 0, 0);
            __builtin_amdgcn_global_load_lds((gbl_u32*)gb, lb, 16, 0, 0);
        }
        __syncthreads();                                     // drains vmcnt; tile resident

        #pragma unroll
        for (int ks = 0; ks < 2; ++ks) {
            s16x8 av[4], bv[4];
            #pragma unroll
            for (int m = 0; m < 4; ++m) {
                const int row = wm + m * 16 + lr;
                av[m] = *(const s16x8*)((const char*)&lsA[0][0] + row * 128 + ((ks * 64 + lg * 16) ^ swz));
            }
            #pragma unroll
            for (int n = 0; n < 4; ++n) {
                const int row = wn + n * 16 + lr;
                bv[n] = *(const s16x8*)((const char*)&lsB[0][0] + row * 128 + ((ks * 64 + lg * 16) ^ swz));
            }
            #pragma unroll
            for (int m = 0; m < 4; ++m)
                #pragma unroll
                for (int n = 0; n < 4; ++n)
                    acc[m][n] = __builtin_amdgcn_mfma_f32_16x16x32_bf16(av[m], bv[n], acc[m][n], 0, 0, 0);
        }
        __syncthreads();                                     // all reads done before next stage
    }

    // ---------------- epilogue: C/D col = lr, row = lg*4 + r  [m89 verified] ----------------
    if constexpr (MODE == 0) {
        const float* bias = (bz == 0) ? bias0 : ((bz == 1) ? bias1 : bias2);
        u8* q8 = (u8*)out0;
        u8* k8 = (u8*)out1;
        #pragma unroll
        for (int m = 0; m < 4; ++m)
        #pragma unroll
        for (int n = 0; n < 4; ++n)
        #pragma unroll
        for (int r = 0; r < 4; ++r) {
            const int grow = by * 128 + wm + m * 16 + lg * 4 + r;   // b*2048+s
            const int gcol = bx * 128 + wn + n * 16 + lr;           // h*512+d
            const float v = acc[m][n][r] + bias[gcol];
            const int bb = grow >> 11, ss = grow & 2047;
            const int hh = gcol >> 9,  dd = gcol & 511;
            if (bz == 0)      q8[(((size_t)(bb * 8 + hh) * 2048 + ss) << 9)  + dd] = f2fp8(v);
            else if (bz == 1) k8[(((size_t)(bb * 8 + hh) * 2048 + ss) << 9)  + dd] = f2fp8(v);
            else              out2[(((size_t)(bb * 8 + hh) * 512  + dd) << 11) + ss] = f2bf(v); // v^T bf16
        }
    } else if constexpr (MODE == 2) {
        const int bh = bh_base + bz;
        const int bb = bh >> 3, hh = bh & 7;
        #pragma unroll
        for (int m = 0; m < 4; ++m)
        #pragma unroll
        for (int r = 0; r < 4; ++r) {
            const int grow = by * 128 + wm + m * 16 + lg * 4 + r;
            const float ri = 1.0f / rsum[bh * 2048 + grow];
            #pragma unroll
            for (int n = 0; n < 4; ++n) {
                const int gcol = bx * 128 + wn + n * 16 + lr;           // 0..511
                out0[((size_t)(bb * 2048 + grow) << 12) + hh * 512 + gcol] = f2bf(acc[m][n][r] * ri);
            }
        }
    } else {
        #pragma unroll
        for (int m = 0; m < 4; ++m)
        #pragma unroll
        for (int n = 0; n < 4; ++n)
        #pragma unroll
        for (int r = 0; r < 4; ++r) {
            const int grow = by * 128 + wm + m * 16 + lg * 4 + r;       // 0..4095
            const int gcol = bx * 128 + wn + n * 16 + lr;               // 0..511
            outf[(size_t)bz * 2097152 + (size_t)grow * 512 + gcol] = acc[m][n][r];
        }
    }
}

// ================= fp8 QK^T: P = exp(q k^T * scale), rowsum-atomic =================
// 128x128 tile, BK=128 fp8 (same 128 B/row & verified 16B-slot XOR swizzle as the
// bf16 BK=64 template), 32 KiB LDS, 4 waves, (256,3), plain __syncthreads loop.
// AI = 128 FLOP/staged-byte (2x bf16) -> compute-bound. K=512 -> 4 K-tiles.
__global__ __launch_bounds__(256, 3) void k_qk(
    const u8* __restrict__ qp, const u8* __restrict__ kp,
    u16* __restrict__ P, float* __restrict__ rsum, int bh_base)
{
    __shared__ u8 lsA[128][128];       // 16 KiB
    __shared__ u8 lsB[128][128];       // 16 KiB

    const int tid = threadIdx.x;
    const int bx = blockIdx.x, by = blockIdx.y, bz = blockIdx.z;
    const int bh = bh_base + bz;

    const u8* A  = qp + (size_t)bh * 1048576 + (size_t)by * 128 * 512;
    const u8* Bt = kp + (size_t)bh * 1048576 + (size_t)bx * 128 * 512;

    const int l  = tid & 63, w = tid >> 6;
    const int wm = (w >> 1) * 64, wn = (w & 1) * 64;
    const int lg = l >> 4, lr = l & 15;
    const int swz = (lr & 7) << 4;

    f32x4 acc[4][4];
    #pragma unroll
    for (int m = 0; m < 4; ++m)
        #pragma unroll
        for (int n = 0; n < 4; ++n)
            #pragma unroll
            for (int r = 0; r < 4; ++r) acc[m][n][r] = 0.f;

    for (int t = 0; t < 4; ++t) {
        const int koff = t * 128;
        // stage: A/B 16 KB each, 4 rounds; linear LDS dest, inverse-swizzled source
        #pragma unroll
        for (int i = 0; i < 4; ++i) {
            const int a   = (i * 256 + tid) * 16;            // linear byte in 16KB region
            const int row = a >> 7;                          // 0..127
            const int cb  = (a & 127) ^ ((row & 7) << 4);    // logical byte-in-row (=elem)
            const u8* ga = A  + (size_t)row * 512 + koff + cb;
            const u8* gb = Bt + (size_t)row * 512 + koff + cb;
            lds_u32* la = (lds_u32*)((char*)&lsA[0][0] + i * 4096 + (w << 10));
            lds_u32* lb = (lds_u32*)((char*)&lsB[0][0] + i * 4096 + (w << 10));
            __builtin_amdgcn_global_load_lds((gbl_u32*)ga, la, 16, 0, 0);
            __builtin_amdgcn_global_load_lds((gbl_u32*)gb, lb, 16, 0, 0);
        }
        __syncthreads();

        // compute: 4 k-slices (K=32 each) x 16 MFMA
        #pragma unroll
        for (int ks = 0; ks < 4; ++ks) {
            const int off = ks * 32 + lg * 8;
            const int po  = ((off & 0x70) ^ swz) | (off & 8);   // swizzle at 16B slots
            long av[4], bv[4];
            #pragma unroll
            for (int m = 0; m < 4; ++m) {
                const int row = wm + m * 16 + lr;
                av[m] = *(const long*)((const char*)&lsA[0][0] + row * 128 + po);
            }
            #pragma unroll
            for (int n = 0; n < 4; ++n) {
                const int row = wn + n * 16 + lr;
                bv[n] = *(const long*)((const char*)&lsB[0][0] + row * 128 + po);
            }
            #pragma unroll
            for (int m = 0; m < 4; ++m)
                #pragma unroll
                for (int n = 0; n < 4; ++n)
                    acc[m][n] = __builtin_amdgcn_mfma_f32_16x16x32_fp8_fp8(av[m], bv[n], acc[m][n], 0, 0, 0);
        }
        __syncthreads();
    }

    // epilogue: P = exp(acc*scale) bf16 + fused rowsum (same as verified MODE-1)
    u16* Pp = P + (size_t)bz * 4194304;
    #pragma unroll
    for (int m = 0; m < 4; ++m)
    #pragma unroll
    for (int r = 0; r < 4; ++r) {
        const int grow = by * 128 + wm + m * 16 + lg * 4 + r;
        float rs = 0.f;
        #pragma unroll
        for (int n = 0; n < 4; ++n) {
            const int gcol = bx * 128 + wn + n * 16 + lr;
            float p = __expf(acc[m][n][r] * 0.04419417382415922f);  // 1/sqrt(512)
            rs += p;
            Pp[((size_t)grow << 11) + gcol] = f2bf(p);
        }
        #pragma unroll
        for (int o = 1; o < 16; o <<= 1) rs += __shfl_xor(rs, o, 64);
        if (lr == 0) atomicAdd(&rsum[bh * 2048 + grow], rs);
    }
}

extern "C" void kernel_launch(void* const* d_in, const int* in_sizes, int n_in,
                              void* d_out, int out_size, void* d_ws, size_t ws_size,
                              hipStream_t stream) {
    const float* Q  = (const float*)d_in[0];
    const float* K  = (const float*)d_in[1];
    const float* V  = (const float*)d_in[2];
    const float* bq = (const float*)d_in[4];
    const float* bk = (const float*)d_in[6];
    const float* bv = (const float*)d_in[8];
    const float* bo = (const float*)d_in[10];
    const float* Wq = (const float*)d_in[3];
    const float* Wk = (const float*)d_in[5];
    const float* Wv = (const float*)d_in[7];
    const float* Wo = (const float*)d_in[9];
    float* out = (float*)d_out;

    char* ws = (char*)d_ws;
    u16*   qkvbf = (u16*)  (ws + 0);            // [3][4096][512] bf16
    u16*   Wt    = (u16*)  (ws + 12582912);     // Wq^T,Wk^T,Wv^T [3][4096][512]
    u16*   WoT   = (u16*)  (ws + 25165824);     // Wo^T [512][4096]
    float* rsum  = (float*)(ws + 29360128);     // [16][2048]
    u8*    qproj = (u8*)   (ws + 29491200);     // [B,H,S,512] fp8
    u8*    kproj = (u8*)   (ws + 63045632);     // [B,H,S,512] fp8
    u16*   vT    = (u16*)  (ws + 96600064);     // [B,H,512,S] bf16
    u16*   Oattn = (u16*)  (ws + 130154496);    // [B*S][4096] bf16
    u16*   P     = (u16*)  (ws + 163708928);    // chunked [ch][2048][2048] bf16
    float* part  = (float*)(ws + 163708928);    // reused after attn: [splitk][4096][512] f32

    size_t avail = (ws_size > (size_t)163708928) ? ws_size - (size_t)163708928 : 0;
    int hp = (int)(avail / 8388608);
    if (hp < 1)  hp = 1;
    if (hp > 16) hp = 16;
    int splitk = (hp >= 8) ? 8 : (hp >= 4) ? 4 : (hp >= 2) ? 2 : 1;

    // input converts (fused launches)
    k_cvt3<<<6144, 256, 0, stream>>>(Q, K, V, qkvbf);
    dim3 tb(32, 8);
    k_tcvt3<<<dim3(128, 16, 3), tb, 0, stream>>>(Wq, Wk, Wv, Wt);
    k_tcvt<<<dim3(16, 128), tb, 0, stream>>>(Wo, WoT, 4096, 512);
    k_zero<<<128, 256, 0, stream>>>(rsum, 32768);

    // fused QKV projections (+bias): q,k -> fp8 [B,H,S,D]; v -> bf16 [B,H,D,S]
    k_gemm<0><<<dim3(32, 32, 3), 256, 0, stream>>>(qkvbf, Wt, (u16*)qproj, (u16*)kproj, vT,
                                                   nullptr, bq, bk, bv, nullptr, 0, 8);

    // attention: P = exp(qk^T*scale) via fp8 MFMA with fused row-sums; O = P v / rowsum
    for (int h0 = 0; h0 < 16; h0 += hp) {
        int ch = (16 - h0 < hp) ? (16 - h0) : hp;
        k_qk<<<dim3(16, 16, ch), 256, 0, stream>>>(qproj, kproj, P, rsum, h0);
        k_gemm<2><<<dim3(4, 16, ch), 256, 0, stream>>>(P, vT, Oattn, nullptr, nullptr,
                                                       nullptr, nullptr, nullptr, nullptr,
                                                       rsum, h0, 32);
    }

    // final projection: split-K partials + reduce(+bias) -> f32 out
    k_gemm<3><<<dim3(4, 32, splitk), 256, 0, stream>>>(Oattn, WoT, nullptr, nullptr, nullptr,
                                                       part, nullptr, nullptr, nullptr,
                                                       nullptr, 0, 64 / splitk);
    k_reduce<<<2048, 256, 0, stream>>>(part, bo, out, splitk);
}

// Round 14
// 313.590 us; speedup vs baseline: 1.8066x; 1.1329x over previous
//
#include <hip/hip_runtime.h>
#include <cstdint>
#include <cstddef>

typedef unsigned int u32;
typedef unsigned short u16;
typedef unsigned char u8;
typedef float  f32x4 __attribute__((ext_vector_type(4)));
typedef short  s16x8 __attribute__((ext_vector_type(8)));
typedef unsigned short u16x4 __attribute__((ext_vector_type(4)));

typedef const __attribute__((address_space(1))) u32 gbl_u32;
typedef __attribute__((address_space(3))) u32 lds_u32;

__device__ __forceinline__ u16 f2bf(float f) {          // RNE f32->bf16 (finite inputs)
    u32 u = __builtin_bit_cast(u32, f);
    u = (u + 0x7FFFu + ((u >> 16) & 1u)) >> 16;
    return (u16)u;
}

// RNE f32 -> fp8 e4m3fn (|f| < 400, finite). Handles subnormals; flushes |f|<2^-9.
__device__ __forceinline__ u8 f2fp8(float f) {
    u32 u = __builtin_bit_cast(u32, f);
    u32 sgn = (u >> 24) & 0x80u;
    float af = __builtin_fabsf(f);
    if (af < 0.001953125f) return (u8)sgn;               // < 2^-9 -> 0
    int ex = (int)((u >> 23) & 0xffu) - 127;
    u32 mant = (u & 0x7fffffu) | 0x800000u;              // 1.m, 24 bits
    int shift = (ex >= -6) ? 20 : (14 - ex);
    u32 keep = mant >> shift;
    u32 rem  = mant & ((1u << shift) - 1u);
    u32 half = 1u << (shift - 1);
    keep += (rem > half || (rem == half && (keep & 1u))) ? 1u : 0u;
    u32 e8, m8;
    if (ex < -6) {                                       // subnormal (units 2^-9), keep in [1..8]
        if (keep >= 8u) { e8 = 1u; m8 = 0u; }
        else            { e8 = 0u; m8 = keep; }
    } else {
        if (keep >= 16u) { keep >>= 1; ex += 1; }
        e8 = (u32)(ex + 7); m8 = keep & 7u;
    }
    return (u8)(sgn | (e8 << 3) | m8);
}

// ---------------- fused elementwise f32 -> bf16 convert (Q,K,V in one launch) ------------
__global__ void k_cvt3(const float* __restrict__ s0, const float* __restrict__ s1,
                       const float* __restrict__ s2, u16* __restrict__ d) {
    int i = blockIdx.x * 256 + threadIdx.x;              // float4 id, 3*524288 total
    int seg = i >> 19, off = i & 524287;
    const float* s = (seg == 0) ? s0 : (seg == 1) ? s1 : s2;
    float4 v = ((const float4*)s)[off];
    u16x4 o = { f2bf(v.x), f2bf(v.y), f2bf(v.z), f2bf(v.w) };
    *(u16x4*)(d + (size_t)i * 4) = o;
}

// ------- batched transpose+convert: W[bz] f32 [R][C] -> bf16 [C][R] (R=512, C=4096) ------
__global__ void k_tcvt3(const float* __restrict__ s0, const float* __restrict__ s1,
                        const float* __restrict__ s2, u16* __restrict__ d) {
    __shared__ float t[32][33];
    const int R = 512, C = 4096;
    int bx = blockIdx.x, by = blockIdx.y, bz = blockIdx.z;
    const float* s = (bz == 0) ? s0 : (bz == 1) ? s1 : s2;
    u16* dd = d + (size_t)bz * 2097152;
    int tx = threadIdx.x, ty = threadIdx.y;
    #pragma unroll
    for (int j = ty; j < 32; j += 8)
        t[j][tx] = s[(size_t)(by * 32 + j) * C + bx * 32 + tx];
    __syncthreads();
    #pragma unroll
    for (int j = ty; j < 32; j += 8)
        dd[(size_t)(bx * 32 + j) * R + by * 32 + tx] = f2bf(t[tx][j]);
}

// ---------------- transpose + convert: src f32 [R][C] -> dst bf16 [C][R] ----------------
__global__ void k_tcvt(const float* __restrict__ s, u16* __restrict__ d, int R, int C) {
    __shared__ float t[32][33];
    int bx = blockIdx.x, by = blockIdx.y;
    int tx = threadIdx.x, ty = threadIdx.y;
    #pragma unroll
    for (int j = ty; j < 32; j += 8)
        t[j][tx] = s[(size_t)(by * 32 + j) * C + bx * 32 + tx];
    __syncthreads();
    #pragma unroll
    for (int j = ty; j < 32; j += 8)
        d[(size_t)(bx * 32 + j) * R + by * 32 + tx] = f2bf(t[tx][j]);
}

__global__ void k_zero(float* __restrict__ p, int n) {
    int i = blockIdx.x * 256 + threadIdx.x;
    if (i < n) p[i] = 0.f;
}

// final reduce: out = bias + sum over splitk partials   (2097152 f32 = 524288 float4)
__global__ void k_reduce(const float* __restrict__ part, const float* __restrict__ bias,
                         float* __restrict__ out, int splitk) {
    int i = blockIdx.x * 256 + threadIdx.x;          // float4 id
    float4 s = ((const float4*)bias)[i & 127];
    for (int j = 0; j < splitk; ++j) {
        float4 p = ((const float4*)part)[(size_t)j * 524288 + i];
        s.x += p.x; s.y += p.y; s.z += p.z; s.w += p.w;
    }
    ((float4*)out)[i] = s;
}

// ================= 128x128xK bf16 GEMM, B given transposed [N][K] ==================
// r7-verified structure: 4 waves (2x2), BK=64, single-buffered 32 KiB LDS, plain
// __syncthreads 2-barrier loop, 3 blocks/CU, 0-conflict XOR swizzle, width-16 loads.
// MODE 0: QKV projections (bz=mat; q,k out fp8, v out bf16 transposed)
// MODE 2: O=(P v)/rowsum            MODE 3: split-K partials of Oattn@Wo
template<int MODE>
__global__ __launch_bounds__(256, 3) void k_gemm(
    const u16* __restrict__ Abase, const u16* __restrict__ Bbase,
    u16* __restrict__ out0, u16* __restrict__ out1, u16* __restrict__ out2,
    float* __restrict__ outf,
    const float* __restrict__ bias0, const float* __restrict__ bias1,
    const float* __restrict__ bias2,
    float* __restrict__ rsum, int bh_base, int ktiles)
{
    constexpr int LDA = (MODE == 2) ? 2048 : (MODE == 3) ? 4096 : 512;
    constexpr int LDB = (MODE == 2) ? 2048 : (MODE == 3) ? 4096 : 512;

    __shared__ u16 lsA[128][64];       // 16 KiB
    __shared__ u16 lsB[128][64];       // 16 KiB

    const int tid = threadIdx.x;
    const int bx = blockIdx.x, by = blockIdx.y, bz = blockIdx.z;

    const u16* A; const u16* Bt;
    if constexpr (MODE == 0) {
        A  = Abase + (size_t)bz * 2097152 + (size_t)by * 128 * 512;
        Bt = Bbase + (size_t)bz * 2097152 + (size_t)bx * 128 * 512;
    } else if constexpr (MODE == 2) {
        int bh = bh_base + bz;
        A  = Abase + (size_t)bz * 4194304 + (size_t)by * 128 * 2048;
        Bt = Bbase + (size_t)bh * 1048576 + (size_t)bx * 128 * 2048;
    } else {
        A  = Abase + (size_t)by * 128 * 4096 + (size_t)bz * (ktiles * 64);
        Bt = Bbase + (size_t)bx * 128 * 4096 + (size_t)bz * (ktiles * 64);
    }

    const int l  = tid & 63, w = tid >> 6;
    const int wm = (w >> 1) * 64, wn = (w & 1) * 64;         // wave tile origin
    const int lg = l >> 4, lr = l & 15;
    const int swz = (lr & 7) << 4;

    f32x4 acc[4][4];
    #pragma unroll
    for (int m = 0; m < 4; ++m)
        #pragma unroll
        for (int n = 0; n < 4; ++n)
            #pragma unroll
            for (int r = 0; r < 4; ++r) acc[m][n][r] = 0.f;

    for (int t = 0; t < ktiles; ++t) {
        const int koff = t * 64;
        #pragma unroll
        for (int i = 0; i < 4; ++i) {
            const int a   = (i * 256 + tid) * 16;            // linear byte in 16KB region
            const int row = a >> 7;                          // 0..127
            const int cb  = (a & 127) ^ ((row & 7) << 4);    // logical byte-in-row
            const u16* ga = A  + (size_t)row * LDA + koff + (cb >> 1);
            const u16* gb = Bt + (size_t)row * LDB + koff + (cb >> 1);
            lds_u32* la = (lds_u32*)((char*)&lsA[0][0] + i * 4096 + (w << 10));
            lds_u32* lb = (lds_u32*)((char*)&lsB[0][0] + i * 4096 + (w << 10));
            __builtin_amdgcn_global_load_lds((gbl_u32*)ga, la, 16, 0, 0);
            __builtin_amdgcn_global_load_lds((gbl_u32*)gb, lb, 16, 0, 0);
        }
        __syncthreads();                                     // drains vmcnt; tile resident

        #pragma unroll
        for (int ks = 0; ks < 2; ++ks) {
            s16x8 av[4], bv[4];
            #pragma unroll
            for (int m = 0; m < 4; ++m) {
                const int row = wm + m * 16 + lr;
                av[m] = *(const s16x8*)((const char*)&lsA[0][0] + row * 128 + ((ks * 64 + lg * 16) ^ swz));
            }
            #pragma unroll
            for (int n = 0; n < 4; ++n) {
                const int row = wn + n * 16 + lr;
                bv[n] = *(const s16x8*)((const char*)&lsB[0][0] + row * 128 + ((ks * 64 + lg * 16) ^ swz));
            }
            #pragma unroll
            for (int m = 0; m < 4; ++m)
                #pragma unroll
                for (int n = 0; n < 4; ++n)
                    acc[m][n] = __builtin_amdgcn_mfma_f32_16x16x32_bf16(av[m], bv[n], acc[m][n], 0, 0, 0);
        }
        __syncthreads();                                     // all reads done before next stage
    }

    // ---------------- epilogue: C/D col = lr, row = lg*4 + r  [m89 verified] ----------------
    if constexpr (MODE == 0) {
        // bz is block-uniform: hoist the 3-way target select OUT of the unrolled loops
        // (r13 had it inside -> 64 replicated branch bodies -> icache/VALU blowup).
        const float* bias = (bz == 0) ? bias0 : ((bz == 1) ? bias1 : bias2);
        if (bz < 2) {                                        // q or k -> fp8, same indexing
            u8* d8 = (u8*)((bz == 0) ? out0 : out1);
            #pragma unroll
            for (int m = 0; m < 4; ++m)
            #pragma unroll
            for (int n = 0; n < 4; ++n)
            #pragma unroll
            for (int r = 0; r < 4; ++r) {
                const int grow = by * 128 + wm + m * 16 + lg * 4 + r;   // b*2048+s
                const int gcol = bx * 128 + wn + n * 16 + lr;           // h*512+d
                const float v = acc[m][n][r] + bias[gcol];
                const int bb = grow >> 11, ss = grow & 2047;
                const int hh = gcol >> 9,  dd = gcol & 511;
                d8[(((size_t)(bb * 8 + hh) * 2048 + ss) << 9) + dd] = f2fp8(v);
            }
        } else {                                             // v -> bf16 transposed
            #pragma unroll
            for (int m = 0; m < 4; ++m)
            #pragma unroll
            for (int n = 0; n < 4; ++n)
            #pragma unroll
            for (int r = 0; r < 4; ++r) {
                const int grow = by * 128 + wm + m * 16 + lg * 4 + r;
                const int gcol = bx * 128 + wn + n * 16 + lr;
                const float v = acc[m][n][r] + bias[gcol];
                const int bb = grow >> 11, ss = grow & 2047;
                const int hh = gcol >> 9,  dd = gcol & 511;
                out2[(((size_t)(bb * 8 + hh) * 512 + dd) << 11) + ss] = f2bf(v);
            }
        }
    } else if constexpr (MODE == 2) {
        const int bh = bh_base + bz;
        const int bb = bh >> 3, hh = bh & 7;
        #pragma unroll
        for (int m = 0; m < 4; ++m)
        #pragma unroll
        for (int r = 0; r < 4; ++r) {
            const int grow = by * 128 + wm + m * 16 + lg * 4 + r;
            const float ri = 1.0f / rsum[bh * 2048 + grow];
            #pragma unroll
            for (int n = 0; n < 4; ++n) {
                const int gcol = bx * 128 + wn + n * 16 + lr;           // 0..511
                out0[((size_t)(bb * 2048 + grow) << 12) + hh * 512 + gcol] = f2bf(acc[m][n][r] * ri);
            }
        }
    } else {
        #pragma unroll
        for (int m = 0; m < 4; ++m)
        #pragma unroll
        for (int n = 0; n < 4; ++n)
        #pragma unroll
        for (int r = 0; r < 4; ++r) {
            const int grow = by * 128 + wm + m * 16 + lg * 4 + r;       // 0..4095
            const int gcol = bx * 128 + wn + n * 16 + lr;               // 0..511
            outf[(size_t)bz * 2097152 + (size_t)grow * 512 + gcol] = acc[m][n][r];
        }
    }
}

// ================= fp8 QK^T: P = exp(q k^T * scale), rowsum-atomic =================
// 128x128 tile, BK=128 fp8 (same 128 B/row & verified 16B-slot XOR swizzle as the
// bf16 BK=64 template), 32 KiB LDS, 4 waves, (256,3), plain __syncthreads loop.
// AI = 128 FLOP/staged-byte (2x bf16) -> compute-bound. K=512 -> 4 K-tiles.
__global__ __launch_bounds__(256, 3) void k_qk(
    const u8* __restrict__ qp, const u8* __restrict__ kp,
    u16* __restrict__ P, float* __restrict__ rsum, int bh_base)
{
    __shared__ u8 lsA[128][128];       // 16 KiB
    __shared__ u8 lsB[128][128];       // 16 KiB

    const int tid = threadIdx.x;
    const int bx = blockIdx.x, by = blockIdx.y, bz = blockIdx.z;
    const int bh = bh_base + bz;

    const u8* A  = qp + (size_t)bh * 1048576 + (size_t)by * 128 * 512;
    const u8* Bt = kp + (size_t)bh * 1048576 + (size_t)bx * 128 * 512;

    const int l  = tid & 63, w = tid >> 6;
    const int wm = (w >> 1) * 64, wn = (w & 1) * 64;
    const int lg = l >> 4, lr = l & 15;
    const int swz = (lr & 7) << 4;

    f32x4 acc[4][4];
    #pragma unroll
    for (int m = 0; m < 4; ++m)
        #pragma unroll
        for (int n = 0; n < 4; ++n)
            #pragma unroll
            for (int r = 0; r < 4; ++r) acc[m][n][r] = 0.f;

    for (int t = 0; t < 4; ++t) {
        const int koff = t * 128;
        // stage: A/B 16 KB each, 4 rounds; linear LDS dest, inverse-swizzled source
        #pragma unroll
        for (int i = 0; i < 4; ++i) {
            const int a   = (i * 256 + tid) * 16;            // linear byte in 16KB region
            const int row = a >> 7;                          // 0..127
            const int cb  = (a & 127) ^ ((row & 7) << 4);    // logical byte-in-row (=elem)
            const u8* ga = A  + (size_t)row * 512 + koff + cb;
            const u8* gb = Bt + (size_t)row * 512 + koff + cb;
            lds_u32* la = (lds_u32*)((char*)&lsA[0][0] + i * 4096 + (w << 10));
            lds_u32* lb = (lds_u32*)((char*)&lsB[0][0] + i * 4096 + (w << 10));
            __builtin_amdgcn_global_load_lds((gbl_u32*)ga, la, 16, 0, 0);
            __builtin_amdgcn_global_load_lds((gbl_u32*)gb, lb, 16, 0, 0);
        }
        __syncthreads();

        // compute: 4 k-slices (K=32 each) x 16 MFMA
        #pragma unroll
        for (int ks = 0; ks < 4; ++ks) {
            const int off = ks * 32 + lg * 8;
            const int po  = ((off & 0x70) ^ swz) | (off & 8);   // swizzle at 16B slots
            long av[4], bv[4];
            #pragma unroll
            for (int m = 0; m < 4; ++m) {
                const int row = wm + m * 16 + lr;
                av[m] = *(const long*)((const char*)&lsA[0][0] + row * 128 + po);
            }
            #pragma unroll
            for (int n = 0; n < 4; ++n) {
                const int row = wn + n * 16 + lr;
                bv[n] = *(const long*)((const char*)&lsB[0][0] + row * 128 + po);
            }
            #pragma unroll
            for (int m = 0; m < 4; ++m)
                #pragma unroll
                for (int n = 0; n < 4; ++n)
                    acc[m][n] = __builtin_amdgcn_mfma_f32_16x16x32_fp8_fp8(av[m], bv[n], acc[m][n], 0, 0, 0);
        }
        __syncthreads();
    }

    // epilogue: P = exp(acc*scale) bf16 + fused rowsum (same as verified MODE-1)
    u16* Pp = P + (size_t)bz * 4194304;
    #pragma unroll
    for (int m = 0; m < 4; ++m)
    #pragma unroll
    for (int r = 0; r < 4; ++r) {
        const int grow = by * 128 + wm + m * 16 + lg * 4 + r;
        float rs = 0.f;
        #pragma unroll
        for (int n = 0; n < 4; ++n) {
            const int gcol = bx * 128 + wn + n * 16 + lr;
            float p = __expf(acc[m][n][r] * 0.04419417382415922f);  // 1/sqrt(512)
            rs += p;
            Pp[((size_t)grow << 11) + gcol] = f2bf(p);
        }
        #pragma unroll
        for (int o = 1; o < 16; o <<= 1) rs += __shfl_xor(rs, o, 64);
        if (lr == 0) atomicAdd(&rsum[bh * 2048 + grow], rs);
    }
}

extern "C" void kernel_launch(void* const* d_in, const int* in_sizes, int n_in,
                              void* d_out, int out_size, void* d_ws, size_t ws_size,
                              hipStream_t stream) {
    const float* Q  = (const float*)d_in[0];
    const float* K  = (const float*)d_in[1];
    const float* V  = (const float*)d_in[2];
    const float* bq = (const float*)d_in[4];
    const float* bk = (const float*)d_in[6];
    const float* bv = (const float*)d_in[8];
    const float* bo = (const float*)d_in[10];
    const float* Wq = (const float*)d_in[3];
    const float* Wk = (const float*)d_in[5];
    const float* Wv = (const float*)d_in[7];
    const float* Wo = (const float*)d_in[9];
    float* out = (float*)d_out;

    char* ws = (char*)d_ws;
    u16*   qkvbf = (u16*)  (ws + 0);            // [3][4096][512] bf16
    u16*   Wt    = (u16*)  (ws + 12582912);     // Wq^T,Wk^T,Wv^T [3][4096][512]
    u16*   WoT   = (u16*)  (ws + 25165824);     // Wo^T [512][4096]
    float* rsum  = (float*)(ws + 29360128);     // [16][2048]
    u8*    qproj = (u8*)   (ws + 29491200);     // [B,H,S,512] fp8
    u8*    kproj = (u8*)   (ws + 63045632);     // [B,H,S,512] fp8
    u16*   vT    = (u16*)  (ws + 96600064);     // [B,H,512,S] bf16
    u16*   Oattn = (u16*)  (ws + 130154496);    // [B*S][4096] bf16
    u16*   P     = (u16*)  (ws + 163708928);    // chunked [ch][2048][2048] bf16
    float* part  = (float*)(ws + 163708928);    // reused after attn: [splitk][4096][512] f32

    size_t avail = (ws_size > (size_t)163708928) ? ws_size - (size_t)163708928 : 0;
    int hp = (int)(avail / 8388608);
    if (hp < 1)  hp = 1;
    if (hp > 16) hp = 16;
    int splitk = (hp >= 4) ? 4 : (hp >= 2) ? 2 : 1;      // 4 = 2 blocks/CU, 34 MB partials

    // input converts (fused launches)
    k_cvt3<<<6144, 256, 0, stream>>>(Q, K, V, qkvbf);
    dim3 tb(32, 8);
    k_tcvt3<<<dim3(128, 16, 3), tb, 0, stream>>>(Wq, Wk, Wv, Wt);
    k_tcvt<<<dim3(16, 128), tb, 0, stream>>>(Wo, WoT, 4096, 512);
    k_zero<<<128, 256, 0, stream>>>(rsum, 32768);

    // fused QKV projections (+bias): q,k -> fp8 [B,H,S,D]; v -> bf16 [B,H,D,S]
    k_gemm<0><<<dim3(32, 32, 3), 256, 0, stream>>>(qkvbf, Wt, (u16*)qproj, (u16*)kproj, vT,
                                                   nullptr, bq, bk, bv, nullptr, 0, 8);

    // attention: P = exp(qk^T*scale) via fp8 MFMA with fused row-sums; O = P v / rowsum
    for (int h0 = 0; h0 < 16; h0 += hp) {
        int ch = (16 - h0 < hp) ? (16 - h0) : hp;
        k_qk<<<dim3(16, 16, ch), 256, 0, stream>>>(qproj, kproj, P, rsum, h0);
        k_gemm<2><<<dim3(4, 16, ch), 256, 0, stream>>>(P, vT, Oattn, nullptr, nullptr,
                                                       nullptr, nullptr, nullptr, nullptr,
                                                       rsum, h0, 32);
    }

    // final projection: split-K partials + reduce(+bias) -> f32 out
    k_gemm<3><<<dim3(4, 32, splitk), 256, 0, stream>>>(Oattn, WoT, nullptr, nullptr, nullptr,
                                                       part, nullptr, nullptr, nullptr,
                                                       nullptr, 0, 64 / splitk);
    k_reduce<<<2048, 256, 0, stream>>>(part, bo, out, splitk);
}

// Round 15
// 302.597 us; speedup vs baseline: 1.8723x; 1.0363x over previous
//
#include <hip/hip_runtime.h>
#include <cstdint>
#include <cstddef>

typedef unsigned int u32;
typedef unsigned short u16;
typedef unsigned char u8;
typedef float  f32x4 __attribute__((ext_vector_type(4)));
typedef short  s16x8 __attribute__((ext_vector_type(8)));
typedef unsigned short u16x4 __attribute__((ext_vector_type(4)));

typedef const __attribute__((address_space(1))) u32 gbl_u32;
typedef __attribute__((address_space(3))) u32 lds_u32;

__device__ __forceinline__ u16 f2bf(float f) {          // RNE f32->bf16 (finite inputs)
    u32 u = __builtin_bit_cast(u32, f);
    u = (u + 0x7FFFu + ((u >> 16) & 1u)) >> 16;
    return (u16)u;
}

// Branchless RNE f32 -> fp8 e4m3fn for |f| <= ~8 (q/k projection range).
// Flushes |f| < 2^-6 to 0 (2% of N(0,0.58) data, adds ~1.6e-3 to s vs 0.33 spread).
// Hand-verified RNE ties: 1.4375->1.5 (m even), 1.3125->1.25 (m even).
__device__ __forceinline__ u8 f2fp8(float f) {
    u32 u = __builtin_bit_cast(u32, f);
    u32 sgn = (u >> 24) & 0x80u;
    u32 au = u & 0x7fffffffu;
    u32 r = au + 0x7ffffu + ((au >> 20) & 1u);          // RNE into 3-bit mantissa
    u32 val = (((r >> 23) - 120u) << 3) | ((r >> 20) & 7u);
    return (u8)(sgn | (au < 0x3c800000u ? 0u : val));   // |f| < 2^-6 -> 0
}

// ---- fused elementwise f32 -> bf16 convert (Q,K,V in one launch) + rsum zero ----
__global__ void k_cvt3(const float* __restrict__ s0, const float* __restrict__ s1,
                       const float* __restrict__ s2, u16* __restrict__ d,
                       float* __restrict__ rsum) {
    int i = blockIdx.x * 256 + threadIdx.x;              // float4 id, 3*524288 total
    if (i < 32768) rsum[i] = 0.f;                        // [16][2048] rowsum accumulator
    int seg = i >> 19, off = i & 524287;
    const float* s = (seg == 0) ? s0 : (seg == 1) ? s1 : s2;
    float4 v = ((const float4*)s)[off];
    u16x4 o = { f2bf(v.x), f2bf(v.y), f2bf(v.z), f2bf(v.w) };
    *(u16x4*)(d + (size_t)i * 4) = o;
}

// ---- batched transpose+convert: Wq,Wk,Wv f32 [512][4096] -> bf16 [4096][512] (bz<3)
//      and Wo f32 [4096][512] -> bf16 [512][4096] (bz==3, grid roles swapped) ----
__global__ void k_tcvt4(const float* __restrict__ s0, const float* __restrict__ s1,
                        const float* __restrict__ s2, const float* __restrict__ s3,
                        u16* __restrict__ dWt, u16* __restrict__ dWoT) {
    __shared__ float t[32][33];
    int bz = blockIdx.z;
    const float* s; u16* dd; int R, C, bx, by;
    if (bz < 3) {
        s = (bz == 0) ? s0 : (bz == 1) ? s1 : s2;
        dd = dWt + (size_t)bz * 2097152; R = 512; C = 4096;
        bx = blockIdx.x; by = blockIdx.y;                // bx<128, by<16
    } else {
        s = s3; dd = dWoT; R = 4096; C = 512;
        bx = blockIdx.y; by = blockIdx.x;                // bx<16, by<128
    }
    int tx = threadIdx.x, ty = threadIdx.y;
    #pragma unroll
    for (int j = ty; j < 32; j += 8)
        t[j][tx] = s[(size_t)(by * 32 + j) * C + bx * 32 + tx];
    __syncthreads();
    #pragma unroll
    for (int j = ty; j < 32; j += 8)
        dd[(size_t)(bx * 32 + j) * R + by * 32 + tx] = f2bf(t[tx][j]);
}

// final reduce: out = bias + sum over splitk partials   (2097152 f32 = 524288 float4)
__global__ void k_reduce(const float* __restrict__ part, const float* __restrict__ bias,
                         float* __restrict__ out, int splitk) {
    int i = blockIdx.x * 256 + threadIdx.x;          // float4 id
    float4 s = ((const float4*)bias)[i & 127];
    for (int j = 0; j < splitk; ++j) {
        float4 p = ((const float4*)part)[(size_t)j * 524288 + i];
        s.x += p.x; s.y += p.y; s.z += p.z; s.w += p.w;
    }
    ((float4*)out)[i] = s;
}

// ================= 128x128xK bf16 GEMM, B given transposed [N][K] ==================
// r7-verified structure: 4 waves (2x2), BK=64, single-buffered 32 KiB LDS, plain
// __syncthreads 2-barrier loop, 3 blocks/CU, 0-conflict XOR swizzle, width-16 loads.
// MODE 0: QKV projections (bz=mat; q,k out fp8, v out bf16 transposed)
// MODE 2: O=(P v)/rowsum            MODE 3: split-K partials of Oattn@Wo
template<int MODE>
__global__ __launch_bounds__(256, 3) void k_gemm(
    const u16* __restrict__ Abase, const u16* __restrict__ Bbase,
    u16* __restrict__ out0, u16* __restrict__ out1, u16* __restrict__ out2,
    float* __restrict__ outf,
    const float* __restrict__ bias0, const float* __restrict__ bias1,
    const float* __restrict__ bias2,
    float* __restrict__ rsum, int bh_base, int ktiles)
{
    constexpr int LDA = (MODE == 2) ? 2048 : (MODE == 3) ? 4096 : 512;
    constexpr int LDB = (MODE == 2) ? 2048 : (MODE == 3) ? 4096 : 512;

    __shared__ u16 lsA[128][64];       // 16 KiB
    __shared__ u16 lsB[128][64];       // 16 KiB

    const int tid = threadIdx.x;
    const int bx = blockIdx.x, by = blockIdx.y, bz = blockIdx.z;

    const u16* A; const u16* Bt;
    if constexpr (MODE == 0) {
        A  = Abase + (size_t)bz * 2097152 + (size_t)by * 128 * 512;
        Bt = Bbase + (size_t)bz * 2097152 + (size_t)bx * 128 * 512;
    } else if constexpr (MODE == 2) {
        int bh = bh_base + bz;
        A  = Abase + (size_t)bz * 4194304 + (size_t)by * 128 * 2048;
        Bt = Bbase + (size_t)bh * 1048576 + (size_t)bx * 128 * 2048;
    } else {
        A  = Abase + (size_t)by * 128 * 4096 + (size_t)bz * (ktiles * 64);
        Bt = Bbase + (size_t)bx * 128 * 4096 + (size_t)bz * (ktiles * 64);
    }

    const int l  = tid & 63, w = tid >> 6;
    const int wm = (w >> 1) * 64, wn = (w & 1) * 64;         // wave tile origin
    const int lg = l >> 4, lr = l & 15;
    const int swz = (lr & 7) << 4;

    f32x4 acc[4][4];
    #pragma unroll
    for (int m = 0; m < 4; ++m)
        #pragma unroll
        for (int n = 0; n < 4; ++n)
            #pragma unroll
            for (int r = 0; r < 4; ++r) acc[m][n][r] = 0.f;

    for (int t = 0; t < ktiles; ++t) {
        const int koff = t * 64;
        #pragma unroll
        for (int i = 0; i < 4; ++i) {
            const int a   = (i * 256 + tid) * 16;            // linear byte in 16KB region
            const int row = a >> 7;                          // 0..127
            const int cb  = (a & 127) ^ ((row & 7) << 4);    // logical byte-in-row
            const u16* ga = A  + (size_t)row * LDA + koff + (cb >> 1);
            const u16* gb = Bt + (size_t)row * LDB + koff + (cb >> 1);
            lds_u32* la = (lds_u32*)((char*)&lsA[0][0] + i * 4096 + (w << 10));
            lds_u32* lb = (lds_u32*)((char*)&lsB[0][0] + i * 4096 + (w << 10));
            __builtin_amdgcn_global_load_lds((gbl_u32*)ga, la, 16, 0, 0);
            __builtin_amdgcn_global_load_lds((gbl_u32*)gb, lb, 16, 0, 0);
        }
        __syncthreads();                                     // drains vmcnt; tile resident

        #pragma unroll
        for (int ks = 0; ks < 2; ++ks) {
            s16x8 av[4], bv[4];
            #pragma unroll
            for (int m = 0; m < 4; ++m) {
                const int row = wm + m * 16 + lr;
                av[m] = *(const s16x8*)((const char*)&lsA[0][0] + row * 128 + ((ks * 64 + lg * 16) ^ swz));
            }
            #pragma unroll
            for (int n = 0; n < 4; ++n) {
                const int row = wn + n * 16 + lr;
                bv[n] = *(const s16x8*)((const char*)&lsB[0][0] + row * 128 + ((ks * 64 + lg * 16) ^ swz));
            }
            #pragma unroll
            for (int m = 0; m < 4; ++m)
                #pragma unroll
                for (int n = 0; n < 4; ++n)
                    acc[m][n] = __builtin_amdgcn_mfma_f32_16x16x32_bf16(av[m], bv[n], acc[m][n], 0, 0, 0);
        }
        __syncthreads();                                     // all reads done before next stage
    }

    // ---------------- epilogue: C/D col = lr, row = lg*4 + r  [m89 verified] ----------------
    if constexpr (MODE == 0) {
        // bz is block-uniform: target select hoisted OUT of the unrolled loops (r14 win)
        const float* bias = (bz == 0) ? bias0 : ((bz == 1) ? bias1 : bias2);
        if (bz < 2) {                                        // q or k -> fp8, same indexing
            u8* d8 = (u8*)((bz == 0) ? out0 : out1);
            #pragma unroll
            for (int m = 0; m < 4; ++m)
            #pragma unroll
            for (int n = 0; n < 4; ++n)
            #pragma unroll
            for (int r = 0; r < 4; ++r) {
                const int grow = by * 128 + wm + m * 16 + lg * 4 + r;   // b*2048+s
                const int gcol = bx * 128 + wn + n * 16 + lr;           // h*512+d
                const float v = acc[m][n][r] + bias[gcol];
                const int bb = grow >> 11, ss = grow & 2047;
                const int hh = gcol >> 9,  dd = gcol & 511;
                d8[(((size_t)(bb * 8 + hh) * 2048 + ss) << 9) + dd] = f2fp8(v);
            }
        } else {                                             // v -> bf16 transposed
            #pragma unroll
            for (int m = 0; m < 4; ++m)
            #pragma unroll
            for (int n = 0; n < 4; ++n)
            #pragma unroll
            for (int r = 0; r < 4; ++r) {
                const int grow = by * 128 + wm + m * 16 + lg * 4 + r;
                const int gcol = bx * 128 + wn + n * 16 + lr;
                const float v = acc[m][n][r] + bias[gcol];
                const int bb = grow >> 11, ss = grow & 2047;
                const int hh = gcol >> 9,  dd = gcol & 511;
                out2[(((size_t)(bb * 8 + hh) * 512 + dd) << 11) + ss] = f2bf(v);
            }
        }
    } else if constexpr (MODE == 2) {
        const int bh = bh_base + bz;
        const int bb = bh >> 3, hh = bh & 7;
        #pragma unroll
        for (int m = 0; m < 4; ++m)
        #pragma unroll
        for (int r = 0; r < 4; ++r) {
            const int grow = by * 128 + wm + m * 16 + lg * 4 + r;
            const float ri = 1.0f / rsum[bh * 2048 + grow];
            #pragma unroll
            for (int n = 0; n < 4; ++n) {
                const int gcol = bx * 128 + wn + n * 16 + lr;           // 0..511
                out0[((size_t)(bb * 2048 + grow) << 12) + hh * 512 + gcol] = f2bf(acc[m][n][r] * ri);
            }
        }
    } else {
        #pragma unroll
        for (int m = 0; m < 4; ++m)
        #pragma unroll
        for (int n = 0; n < 4; ++n)
        #pragma unroll
        for (int r = 0; r < 4; ++r) {
            const int grow = by * 128 + wm + m * 16 + lg * 4 + r;       // 0..4095
            const int gcol = bx * 128 + wn + n * 16 + lr;               // 0..511
            outf[(size_t)bz * 2097152 + (size_t)grow * 512 + gcol] = acc[m][n][r];
        }
    }
}

// ================= fp8 QK^T: P = exp(q k^T * scale), rowsum-atomic =================
// 128x128 tile, BK=128 fp8 (same 128 B/row & verified 16B-slot XOR swizzle as the
// bf16 BK=64 template), 32 KiB LDS, 4 waves, (256,3), plain __syncthreads loop.
// AI = 128 FLOP/staged-byte (2x bf16) -> compute-bound. K=512 -> 4 K-tiles.
__global__ __launch_bounds__(256, 3) void k_qk(
    const u8* __restrict__ qp, const u8* __restrict__ kp,
    u16* __restrict__ P, float* __restrict__ rsum, int bh_base)
{
    __shared__ u8 lsA[128][128];       // 16 KiB
    __shared__ u8 lsB[128][128];       // 16 KiB

    const int tid = threadIdx.x;
    const int bx = blockIdx.x, by = blockIdx.y, bz = blockIdx.z;
    const int bh = bh_base + bz;

    const u8* A  = qp + (size_t)bh * 1048576 + (size_t)by * 128 * 512;
    const u8* Bt = kp + (size_t)bh * 1048576 + (size_t)bx * 128 * 512;

    const int l  = tid & 63, w = tid >> 6;
    const int wm = (w >> 1) * 64, wn = (w & 1) * 64;
    const int lg = l >> 4, lr = l & 15;
    const int swz = (lr & 7) << 4;

    f32x4 acc[4][4];
    #pragma unroll
    for (int m = 0; m < 4; ++m)
        #pragma unroll
        for (int n = 0; n < 4; ++n)
            #pragma unroll
            for (int r = 0; r < 4; ++r) acc[m][n][r] = 0.f;

    for (int t = 0; t < 4; ++t) {
        const int koff = t * 128;
        // stage: A/B 16 KB each, 4 rounds; linear LDS dest, inverse-swizzled source
        #pragma unroll
        for (int i = 0; i < 4; ++i) {
            const int a   = (i * 256 + tid) * 16;            // linear byte in 16KB region
            const int row = a >> 7;                          // 0..127
            const int cb  = (a & 127) ^ ((row & 7) << 4);    // logical byte-in-row (=elem)
            const u8* ga = A  + (size_t)row * 512 + koff + cb;
            const u8* gb = Bt + (size_t)row * 512 + koff + cb;
            lds_u32* la = (lds_u32*)((char*)&lsA[0][0] + i * 4096 + (w << 10));
            lds_u32* lb = (lds_u32*)((char*)&lsB[0][0] + i * 4096 + (w << 10));
            __builtin_amdgcn_global_load_lds((gbl_u32*)ga, la, 16, 0, 0);
            __builtin_amdgcn_global_load_lds((gbl_u32*)gb, lb, 16, 0, 0);
        }
        __syncthreads();

        // compute: 4 k-slices (K=32 each) x 16 MFMA
        #pragma unroll
        for (int ks = 0; ks < 4; ++ks) {
            const int off = ks * 32 + lg * 8;
            const int po  = ((off & 0x70) ^ swz) | (off & 8);   // swizzle at 16B slots
            long av[4], bv[4];
            #pragma unroll
            for (int m = 0; m < 4; ++m) {
                const int row = wm + m * 16 + lr;
                av[m] = *(const long*)((const char*)&lsA[0][0] + row * 128 + po);
            }
            #pragma unroll
            for (int n = 0; n < 4; ++n) {
                const int row = wn + n * 16 + lr;
                bv[n] = *(const long*)((const char*)&lsB[0][0] + row * 128 + po);
            }
            #pragma unroll
            for (int m = 0; m < 4; ++m)
                #pragma unroll
                for (int n = 0; n < 4; ++n)
                    acc[m][n] = __builtin_amdgcn_mfma_f32_16x16x32_fp8_fp8(av[m], bv[n], acc[m][n], 0, 0, 0);
        }
        __syncthreads();
    }

    // epilogue: P = exp(acc*scale) bf16 + fused rowsum
    u16* Pp = P + (size_t)bz * 4194304;
    #pragma unroll
    for (int m = 0; m < 4; ++m)
    #pragma unroll
    for (int r = 0; r < 4; ++r) {
        const int grow = by * 128 + wm + m * 16 + lg * 4 + r;
        float rs = 0.f;
        #pragma unroll
        for (int n = 0; n < 4; ++n) {
            const int gcol = bx * 128 + wn + n * 16 + lr;
            float p = __expf(acc[m][n][r] * 0.04419417382415922f);  // 1/sqrt(512)
            rs += p;
            Pp[((size_t)grow << 11) + gcol] = f2bf(p);
        }
        #pragma unroll
        for (int o = 1; o < 16; o <<= 1) rs += __shfl_xor(rs, o, 64);
        if (lr == 0) atomicAdd(&rsum[bh * 2048 + grow], rs);
    }
}

extern "C" void kernel_launch(void* const* d_in, const int* in_sizes, int n_in,
                              void* d_out, int out_size, void* d_ws, size_t ws_size,
                              hipStream_t stream) {
    const float* Q  = (const float*)d_in[0];
    const float* K  = (const float*)d_in[1];
    const float* V  = (const float*)d_in[2];
    const float* bq = (const float*)d_in[4];
    const float* bk = (const float*)d_in[6];
    const float* bv = (const float*)d_in[8];
    const float* bo = (const float*)d_in[10];
    const float* Wq = (const float*)d_in[3];
    const float* Wk = (const float*)d_in[5];
    const float* Wv = (const float*)d_in[7];
    const float* Wo = (const float*)d_in[9];
    float* out = (float*)d_out;

    char* ws = (char*)d_ws;
    u16*   qkvbf = (u16*)  (ws + 0);            // [3][4096][512] bf16
    u16*   Wt    = (u16*)  (ws + 12582912);     // Wq^T,Wk^T,Wv^T [3][4096][512]
    u16*   WoT   = (u16*)  (ws + 25165824);     // Wo^T [512][4096]
    float* rsum  = (float*)(ws + 29360128);     // [16][2048]
    u8*    qproj = (u8*)   (ws + 29491200);     // [B,H,S,512] fp8
    u8*    kproj = (u8*)   (ws + 63045632);     // [B,H,S,512] fp8
    u16*   vT    = (u16*)  (ws + 96600064);     // [B,H,512,S] bf16
    u16*   Oattn = (u16*)  (ws + 130154496);    // [B*S][4096] bf16
    u16*   P     = (u16*)  (ws + 163708928);    // chunked [ch][2048][2048] bf16
    float* part  = (float*)(ws + 163708928);    // reused after attn: [splitk][4096][512] f32

    size_t avail = (ws_size > (size_t)163708928) ? ws_size - (size_t)163708928 : 0;
    int hp = (int)(avail / 8388608);
    if (hp < 1)  hp = 1;
    if (hp > 16) hp = 16;
    int splitk = (hp >= 4) ? 4 : (hp >= 2) ? 2 : 1;      // 4 = 2 blocks/CU, 34 MB partials

    // input converts (fused launches; cvt3 also zeroes rsum)
    k_cvt3<<<6144, 256, 0, stream>>>(Q, K, V, qkvbf, rsum);
    dim3 tb(32, 8);
    k_tcvt4<<<dim3(128, 16, 4), tb, 0, stream>>>(Wq, Wk, Wv, Wo, Wt, WoT);

    // fused QKV projections (+bias): q,k -> fp8 [B,H,S,D]; v -> bf16 [B,H,D,S]
    k_gemm<0><<<dim3(32, 32, 3), 256, 0, stream>>>(qkvbf, Wt, (u16*)qproj, (u16*)kproj, vT,
                                                   nullptr, bq, bk, bv, nullptr, 0, 8);

    // attention: P = exp(qk^T*scale) via fp8 MFMA with fused row-sums; O = P v / rowsum
    for (int h0 = 0; h0 < 16; h0 += hp) {
        int ch = (16 - h0 < hp) ? (16 - h0) : hp;
        k_qk<<<dim3(16, 16, ch), 256, 0, stream>>>(qproj, kproj, P, rsum, h0);
        k_gemm<2><<<dim3(4, 16, ch), 256, 0, stream>>>(P, vT, Oattn, nullptr, nullptr,
                                                       nullptr, nullptr, nullptr, nullptr,
                                                       rsum, h0, 32);
    }

    // final projection: split-K partials + reduce(+bias) -> f32 out
    k_gemm<3><<<dim3(4, 32, splitk), 256, 0, stream>>>(Oattn, WoT, nullptr, nullptr, nullptr,
                                                       part, nullptr, nullptr, nullptr,
                                                       nullptr, 0, 64 / splitk);
    k_reduce<<<2048, 256, 0, stream>>>(part, bo, out, splitk);
}

// Round 16
// 286.269 us; speedup vs baseline: 1.9791x; 1.0570x over previous
//
#include <hip/hip_runtime.h>
#include <cstdint>
#include <cstddef>

typedef unsigned int u32;
typedef unsigned short u16;
typedef unsigned char u8;
typedef float  f32x4 __attribute__((ext_vector_type(4)));
typedef short  s16x8 __attribute__((ext_vector_type(8)));
typedef unsigned short u16x4 __attribute__((ext_vector_type(4)));

typedef const __attribute__((address_space(1))) u32 gbl_u32;
typedef __attribute__((address_space(3))) u32 lds_u32;

__device__ __forceinline__ u16 f2bf(float f) {          // RNE f32->bf16 (finite inputs)
    u32 u = __builtin_bit_cast(u32, f);
    u = (u + 0x7FFFu + ((u >> 16) & 1u)) >> 16;
    return (u16)u;
}

// Branchless RNE f32 -> fp8 e4m3fn for |f| <= ~8 (q/k projection range).
// Flushes |f| < 2^-6 to 0 (2% of N(0,0.58) data, adds ~1.6e-3 to s vs 0.33 spread).
__device__ __forceinline__ u8 f2fp8(float f) {
    u32 u = __builtin_bit_cast(u32, f);
    u32 sgn = (u >> 24) & 0x80u;
    u32 au = u & 0x7fffffffu;
    u32 r = au + 0x7ffffu + ((au >> 20) & 1u);          // RNE into 3-bit mantissa
    u32 val = (((r >> 23) - 120u) << 3) | ((r >> 20) & 7u);
    return (u8)(sgn | (au < 0x3c800000u ? 0u : val));   // |f| < 2^-6 -> 0
}

// ---- fused elementwise f32 -> bf16 convert (Q,K,V in one launch) + rsum zero ----
__global__ void k_cvt3(const float* __restrict__ s0, const float* __restrict__ s1,
                       const float* __restrict__ s2, u16* __restrict__ d,
                       float* __restrict__ rsum) {
    int i = blockIdx.x * 256 + threadIdx.x;              // float4 id, 3*524288 total
    if (i < 32768) rsum[i] = 0.f;                        // [16][2048] rowsum accumulator
    int seg = i >> 19, off = i & 524287;
    const float* s = (seg == 0) ? s0 : (seg == 1) ? s1 : s2;
    float4 v = ((const float4*)s)[off];
    u16x4 o = { f2bf(v.x), f2bf(v.y), f2bf(v.z), f2bf(v.w) };
    *(u16x4*)(d + (size_t)i * 4) = o;
}

// ---- batched transpose+convert: Wq,Wk,Wv f32 [512][4096] -> bf16 [4096][512] (bz<3)
//      and Wo f32 [4096][512] -> bf16 [512][4096] (bz==3, grid roles swapped) ----
__global__ void k_tcvt4(const float* __restrict__ s0, const float* __restrict__ s1,
                        const float* __restrict__ s2, const float* __restrict__ s3,
                        u16* __restrict__ dWt, u16* __restrict__ dWoT) {
    __shared__ float t[32][33];
    int bz = blockIdx.z;
    const float* s; u16* dd; int R, C, bx, by;
    if (bz < 3) {
        s = (bz == 0) ? s0 : (bz == 1) ? s1 : s2;
        dd = dWt + (size_t)bz * 2097152; R = 512; C = 4096;
        bx = blockIdx.x; by = blockIdx.y;                // bx<128, by<16
    } else {
        s = s3; dd = dWoT; R = 4096; C = 512;
        bx = blockIdx.y; by = blockIdx.x;                // bx<16, by<128
    }
    int tx = threadIdx.x, ty = threadIdx.y;
    #pragma unroll
    for (int j = ty; j < 32; j += 8)
        t[j][tx] = s[(size_t)(by * 32 + j) * C + bx * 32 + tx];
    __syncthreads();
    #pragma unroll
    for (int j = ty; j < 32; j += 8)
        dd[(size_t)(bx * 32 + j) * R + by * 32 + tx] = f2bf(t[tx][j]);
}

// final reduce: out = bias + sum over splitk partials   (2097152 f32 = 524288 float4)
__global__ void k_reduce(const float* __restrict__ part, const float* __restrict__ bias,
                         float* __restrict__ out, int splitk) {
    int i = blockIdx.x * 256 + threadIdx.x;          // float4 id
    float4 s = ((const float4*)bias)[i & 127];
    for (int j = 0; j < splitk; ++j) {
        float4 p = ((const float4*)part)[(size_t)j * 524288 + i];
        s.x += p.x; s.y += p.y; s.z += p.z; s.w += p.w;
    }
    ((float4*)out)[i] = s;
}

// ================= 128x128xK bf16 GEMM, B given transposed [N][K] ==================
// r7-verified structure: 4 waves (2x2), BK=64, single-buffered 32 KiB LDS, plain
// __syncthreads 2-barrier loop, 3 blocks/CU, 0-conflict XOR swizzle, width-16 loads.
// MODE 0: QKV projections (bz=mat; q,k out fp8, v out bf16 transposed)
// MODE 2: O=(P v)/rowsum            MODE 3: split-K partials of Oattn@Wo
template<int MODE>
__global__ __launch_bounds__(256, 3) void k_gemm(
    const u16* __restrict__ Abase, const u16* __restrict__ Bbase,
    u16* __restrict__ out0, u16* __restrict__ out1, u16* __restrict__ out2,
    float* __restrict__ outf,
    const float* __restrict__ bias0, const float* __restrict__ bias1,
    const float* __restrict__ bias2,
    float* __restrict__ rsum, int bh_base, int ktiles)
{
    constexpr int LDA = (MODE == 2) ? 2048 : (MODE == 3) ? 4096 : 512;
    constexpr int LDB = (MODE == 2) ? 2048 : (MODE == 3) ? 4096 : 512;

    __shared__ u16 lsA[128][64];       // 16 KiB
    __shared__ u16 lsB[128][64];       // 16 KiB

    const int tid = threadIdx.x;
    const int bx = blockIdx.x, by = blockIdx.y, bz = blockIdx.z;

    const u16* A; const u16* Bt;
    if constexpr (MODE == 0) {
        A  = Abase + (size_t)bz * 2097152 + (size_t)by * 128 * 512;
        Bt = Bbase + (size_t)bz * 2097152 + (size_t)bx * 128 * 512;
    } else if constexpr (MODE == 2) {
        int bh = bh_base + bz;
        A  = Abase + (size_t)bz * 4194304 + (size_t)by * 128 * 2048;
        Bt = Bbase + (size_t)bh * 1048576 + (size_t)bx * 128 * 2048;
    } else {
        A  = Abase + (size_t)by * 128 * 4096 + (size_t)bz * (ktiles * 64);
        Bt = Bbase + (size_t)bx * 128 * 4096 + (size_t)bz * (ktiles * 64);
    }

    const int l  = tid & 63, w = tid >> 6;
    const int wm = (w >> 1) * 64, wn = (w & 1) * 64;         // wave tile origin
    const int lg = l >> 4, lr = l & 15;
    const int swz = (lr & 7) << 4;

    f32x4 acc[4][4];
    #pragma unroll
    for (int m = 0; m < 4; ++m)
        #pragma unroll
        for (int n = 0; n < 4; ++n)
            #pragma unroll
            for (int r = 0; r < 4; ++r) acc[m][n][r] = 0.f;

    for (int t = 0; t < ktiles; ++t) {
        const int koff = t * 64;
        #pragma unroll
        for (int i = 0; i < 4; ++i) {
            const int a   = (i * 256 + tid) * 16;            // linear byte in 16KB region
            const int row = a >> 7;                          // 0..127
            const int cb  = (a & 127) ^ ((row & 7) << 4);    // logical byte-in-row
            const u16* ga = A  + (size_t)row * LDA + koff + (cb >> 1);
            const u16* gb = Bt + (size_t)row * LDB + koff + (cb >> 1);
            lds_u32* la = (lds_u32*)((char*)&lsA[0][0] + i * 4096 + (w << 10));
            lds_u32* lb = (lds_u32*)((char*)&lsB[0][0] + i * 4096 + (w << 10));
            __builtin_amdgcn_global_load_lds((gbl_u32*)ga, la, 16, 0, 0);
            __builtin_amdgcn_global_load_lds((gbl_u32*)gb, lb, 16, 0, 0);
        }
        __syncthreads();                                     // drains vmcnt; tile resident

        #pragma unroll
        for (int ks = 0; ks < 2; ++ks) {
            s16x8 av[4], bv[4];
            #pragma unroll
            for (int m = 0; m < 4; ++m) {
                const int row = wm + m * 16 + lr;
                av[m] = *(const s16x8*)((const char*)&lsA[0][0] + row * 128 + ((ks * 64 + lg * 16) ^ swz));
            }
            #pragma unroll
            for (int n = 0; n < 4; ++n) {
                const int row = wn + n * 16 + lr;
                bv[n] = *(const s16x8*)((const char*)&lsB[0][0] + row * 128 + ((ks * 64 + lg * 16) ^ swz));
            }
            #pragma unroll
            for (int m = 0; m < 4; ++m)
                #pragma unroll
                for (int n = 0; n < 4; ++n)
                    acc[m][n] = __builtin_amdgcn_mfma_f32_16x16x32_bf16(av[m], bv[n], acc[m][n], 0, 0, 0);
        }
        __syncthreads();                                     // all reads done before next stage
    }

    // ---------------- epilogue: C/D col = lr, row = lg*4 + r  [m89 verified] ----------------
    if constexpr (MODE == 0) {
        // bz is block-uniform: target select hoisted OUT of the unrolled loops (r14 win)
        const float* bias = (bz == 0) ? bias0 : ((bz == 1) ? bias1 : bias2);
        if (bz < 2) {                                        // q or k -> fp8, same indexing
            u8* d8 = (u8*)((bz == 0) ? out0 : out1);
            #pragma unroll
            for (int m = 0; m < 4; ++m)
            #pragma unroll
            for (int n = 0; n < 4; ++n)
            #pragma unroll
            for (int r = 0; r < 4; ++r) {
                const int grow = by * 128 + wm + m * 16 + lg * 4 + r;   // b*2048+s
                const int gcol = bx * 128 + wn + n * 16 + lr;           // h*512+d
                const float v = acc[m][n][r] + bias[gcol];
                const int bb = grow >> 11, ss = grow & 2047;
                const int hh = gcol >> 9,  dd = gcol & 511;
                d8[(((size_t)(bb * 8 + hh) * 2048 + ss) << 9) + dd] = f2fp8(v);
            }
        } else {                                             // v -> bf16 transposed
            #pragma unroll
            for (int m = 0; m < 4; ++m)
            #pragma unroll
            for (int n = 0; n < 4; ++n)
            #pragma unroll
            for (int r = 0; r < 4; ++r) {
                const int grow = by * 128 + wm + m * 16 + lg * 4 + r;
                const int gcol = bx * 128 + wn + n * 16 + lr;
                const float v = acc[m][n][r] + bias[gcol];
                const int bb = grow >> 11, ss = grow & 2047;
                const int hh = gcol >> 9,  dd = gcol & 511;
                out2[(((size_t)(bb * 8 + hh) * 512 + dd) << 11) + ss] = f2bf(v);
            }
        }
    } else if constexpr (MODE == 2) {
        const int bh = bh_base + bz;
        const int bb = bh >> 3, hh = bh & 7;
        #pragma unroll
        for (int m = 0; m < 4; ++m)
        #pragma unroll
        for (int r = 0; r < 4; ++r) {
            const int grow = by * 128 + wm + m * 16 + lg * 4 + r;
            const float ri = 1.0f / rsum[bh * 2048 + grow];
            #pragma unroll
            for (int n = 0; n < 4; ++n) {
                const int gcol = bx * 128 + wn + n * 16 + lr;           // 0..511
                out0[((size_t)(bb * 2048 + grow) << 12) + hh * 512 + gcol] = f2bf(acc[m][n][r] * ri);
            }
        }
    } else {
        #pragma unroll
        for (int m = 0; m < 4; ++m)
        #pragma unroll
        for (int n = 0; n < 4; ++n)
        #pragma unroll
        for (int r = 0; r < 4; ++r) {
            const int grow = by * 128 + wm + m * 16 + lg * 4 + r;       // 0..4095
            const int gcol = bx * 128 + wn + n * 16 + lr;               // 0..511
            outf[(size_t)bz * 2097152 + (size_t)grow * 512 + gcol] = acc[m][n][r];
        }
    }
}

// ================= fp8 QK^T: P = exp(q k^T * scale), rowsum-atomic =================
// 128x128 tile, BK=128 fp8, 32 KiB LDS, 4 waves, (256,3), plain __syncthreads loop.
// AI = 128 FLOP/staged-byte (2x bf16) -> compute-bound. K=512 -> 4 K-tiles.
__global__ __launch_bounds__(256, 3) void k_qk(
    const u8* __restrict__ qp, const u8* __restrict__ kp,
    u16* __restrict__ P, float* __restrict__ rsum, int bh_base)
{
    __shared__ u8 lsA[128][128];       // 16 KiB
    __shared__ u8 lsB[128][128];       // 16 KiB

    const int tid = threadIdx.x;
    const int bx = blockIdx.x, by = blockIdx.y, bz = blockIdx.z;
    const int bh = bh_base + bz;

    const u8* A  = qp + (size_t)bh * 1048576 + (size_t)by * 128 * 512;
    const u8* Bt = kp + (size_t)bh * 1048576 + (size_t)bx * 128 * 512;

    const int l  = tid & 63, w = tid >> 6;
    const int wm = (w >> 1) * 64, wn = (w & 1) * 64;
    const int lg = l >> 4, lr = l & 15;
    const int swz = (lr & 7) << 4;

    f32x4 acc[4][4];
    #pragma unroll
    for (int m = 0; m < 4; ++m)
        #pragma unroll
        for (int n = 0; n < 4; ++n)
            #pragma unroll
            for (int r = 0; r < 4; ++r) acc[m][n][r] = 0.f;

    for (int t = 0; t < 4; ++t) {
        const int koff = t * 128;
        // stage: A/B 16 KB each, 4 rounds; linear LDS dest, inverse-swizzled source
        #pragma unroll
        for (int i = 0; i < 4; ++i) {
            const int a   = (i * 256 + tid) * 16;            // linear byte in 16KB region
            const int row = a >> 7;                          // 0..127
            const int cb  = (a & 127) ^ ((row & 7) << 4);    // logical byte-in-row (=elem)
            const u8* ga = A  + (size_t)row * 512 + koff + cb;
            const u8* gb = Bt + (size_t)row * 512 + koff + cb;
            lds_u32* la = (lds_u32*)((char*)&lsA[0][0] + i * 4096 + (w << 10));
            lds_u32* lb = (lds_u32*)((char*)&lsB[0][0] + i * 4096 + (w << 10));
            __builtin_amdgcn_global_load_lds((gbl_u32*)ga, la, 16, 0, 0);
            __builtin_amdgcn_global_load_lds((gbl_u32*)gb, lb, 16, 0, 0);
        }
        __syncthreads();

        // compute: 4 k-slices (K=32 each) x 16 MFMA
        #pragma unroll
        for (int ks = 0; ks < 4; ++ks) {
            const int off = ks * 32 + lg * 8;
            const int po  = ((off & 0x70) ^ swz) | (off & 8);   // swizzle at 16B slots
            long av[4], bv[4];
            #pragma unroll
            for (int m = 0; m < 4; ++m) {
                const int row = wm + m * 16 + lr;
                av[m] = *(const long*)((const char*)&lsA[0][0] + row * 128 + po);
            }
            #pragma unroll
            for (int n = 0; n < 4; ++n) {
                const int row = wn + n * 16 + lr;
                bv[n] = *(const long*)((const char*)&lsB[0][0] + row * 128 + po);
            }
            #pragma unroll
            for (int m = 0; m < 4; ++m)
                #pragma unroll
                for (int n = 0; n < 4; ++n)
                    acc[m][n] = __builtin_amdgcn_mfma_f32_16x16x32_fp8_fp8(av[m], bv[n], acc[m][n], 0, 0, 0);
        }
        __syncthreads();
    }

    // epilogue: P = exp(acc*scale) bf16 + fused rowsum
    u16* Pp = P + (size_t)bz * 4194304;
    #pragma unroll
    for (int m = 0; m < 4; ++m)
    #pragma unroll
    for (int r = 0; r < 4; ++r) {
        const int grow = by * 128 + wm + m * 16 + lg * 4 + r;
        float rs = 0.f;
        #pragma unroll
        for (int n = 0; n < 4; ++n) {
            const int gcol = bx * 128 + wn + n * 16 + lr;
            float p = __expf(acc[m][n][r] * 0.04419417382415922f);  // 1/sqrt(512)
            rs += p;
            Pp[((size_t)grow << 11) + gcol] = f2bf(p);
        }
        #pragma unroll
        for (int o = 1; o < 16; o <<= 1) rs += __shfl_xor(rs, o, 64);
        if (lr == 0) atomicAdd(&rsum[bh * 2048 + grow], rs);
    }
}

extern "C" void kernel_launch(void* const* d_in, const int* in_sizes, int n_in,
                              void* d_out, int out_size, void* d_ws, size_t ws_size,
                              hipStream_t stream) {
    const float* Q  = (const float*)d_in[0];
    const float* K  = (const float*)d_in[1];
    const float* V  = (const float*)d_in[2];
    const float* bq = (const float*)d_in[4];
    const float* bk = (const float*)d_in[6];
    const float* bv = (const float*)d_in[8];
    const float* bo = (const float*)d_in[10];
    const float* Wq = (const float*)d_in[3];
    const float* Wk = (const float*)d_in[5];
    const float* Wv = (const float*)d_in[7];
    const float* Wo = (const float*)d_in[9];
    float* out = (float*)d_out;

    char* ws = (char*)d_ws;
    u16*   qkvbf = (u16*)  (ws + 0);            // [3][4096][512] bf16
    u16*   Wt    = (u16*)  (ws + 12582912);     // Wq^T,Wk^T,Wv^T [3][4096][512]
    u16*   WoT   = (u16*)  (ws + 25165824);     // Wo^T [512][4096]
    float* rsum  = (float*)(ws + 29360128);     // [16][2048]
    u8*    qproj = (u8*)   (ws + 29491200);     // [B,H,S,512] fp8
    u8*    kproj = (u8*)   (ws + 63045632);     // [B,H,S,512] fp8
    u16*   vT    = (u16*)  (ws + 96600064);     // [B,H,512,S] bf16
    u16*   Oattn = (u16*)  (ws + 130154496);    // [B*S][4096] bf16
    u16*   P     = (u16*)  (ws + 163708928);    // chunked [ch][2048][2048] bf16
    float* part  = (float*)(ws + 163708928);    // reused after attn: [splitk][4096][512] f32

    size_t avail = (ws_size > (size_t)163708928) ? ws_size - (size_t)163708928 : 0;
    int hp = (int)(avail / 8388608);
    if (hp < 1) hp = 1;
    if (hp > 8) hp = 8;      // L3-block: P chunk 67 MB -> attention working set ~170 MB < 256 MB L3
    int splitk = (hp >= 4) ? 4 : (hp >= 2) ? 2 : 1;      // 4 = 2 blocks/CU, 34 MB partials

    // input converts (fused launches; cvt3 also zeroes rsum)
    k_cvt3<<<6144, 256, 0, stream>>>(Q, K, V, qkvbf, rsum);
    dim3 tb(32, 8);
    k_tcvt4<<<dim3(128, 16, 4), tb, 0, stream>>>(Wq, Wk, Wv, Wo, Wt, WoT);

    // fused QKV projections (+bias): q,k -> fp8 [B,H,S,D]; v -> bf16 [B,H,D,S]
    k_gemm<0><<<dim3(32, 32, 3), 256, 0, stream>>>(qkvbf, Wt, (u16*)qproj, (u16*)kproj, vT,
                                                   nullptr, bq, bk, bv, nullptr, 0, 8);

    // attention: P = exp(qk^T*scale) via fp8 MFMA with fused row-sums; O = P v / rowsum
    for (int h0 = 0; h0 < 16; h0 += hp) {
        int ch = (16 - h0 < hp) ? (16 - h0) : hp;
        k_qk<<<dim3(16, 16, ch), 256, 0, stream>>>(qproj, kproj, P, rsum, h0);
        k_gemm<2><<<dim3(4, 16, ch), 256, 0, stream>>>(P, vT, Oattn, nullptr, nullptr,
                                                       nullptr, nullptr, nullptr, nullptr,
                                                       rsum, h0, 32);
    }

    // final projection: split-K partials + reduce(+bias) -> f32 out
    k_gemm<3><<<dim3(4, 32, splitk), 256, 0, stream>>>(Oattn, WoT, nullptr, nullptr, nullptr,
                                                       part, nullptr, nullptr, nullptr,
                                                       nullptr, 0, 64 / splitk);
    k_reduce<<<2048, 256, 0, stream>>>(part, bo, out, splitk);
}

// Round 17
// 281.374 us; speedup vs baseline: 2.0135x; 1.0174x over previous
//
#include <hip/hip_runtime.h>
#include <cstdint>
#include <cstddef>

typedef unsigned int u32;
typedef unsigned short u16;
typedef unsigned char u8;
typedef float  f32x4 __attribute__((ext_vector_type(4)));
typedef short  s16x8 __attribute__((ext_vector_type(8)));
typedef unsigned short u16x4 __attribute__((ext_vector_type(4)));

typedef const __attribute__((address_space(1))) u32 gbl_u32;
typedef __attribute__((address_space(3))) u32 lds_u32;

__device__ __forceinline__ u16 f2bf(float f) {          // RNE f32->bf16 (finite inputs)
    u32 u = __builtin_bit_cast(u32, f);
    u = (u + 0x7FFFu + ((u >> 16) & 1u)) >> 16;
    return (u16)u;
}

// Branchless RNE f32 -> fp8 e4m3fn for |f| < ~448. Flushes |f| < 2^-6 to 0.
__device__ __forceinline__ u8 f2fp8(float f) {
    u32 u = __builtin_bit_cast(u32, f);
    u32 sgn = (u >> 24) & 0x80u;
    u32 au = u & 0x7fffffffu;
    u32 r = au + 0x7ffffu + ((au >> 20) & 1u);          // RNE into 3-bit mantissa
    u32 val = (((r >> 23) - 120u) << 3) | ((r >> 20) & 7u);
    return (u8)(sgn | (au < 0x3c800000u ? 0u : val));   // |f| < 2^-6 -> 0
}

// ---- fused input convert: Q,K -> fp8 (x8 scale), V -> bf16; zero rsum ----
__global__ void k_cvt3(const float* __restrict__ s0, const float* __restrict__ s1,
                       const float* __restrict__ s2,
                       u8* __restrict__ q8, u8* __restrict__ k8, u16* __restrict__ vbf,
                       float* __restrict__ rsum) {
    int i = blockIdx.x * 256 + threadIdx.x;              // float4 id, 3*524288 total
    if (i < 32768) rsum[i] = 0.f;                        // [16][2048] rowsum accumulator
    int seg = i >> 19, off = i & 524287;
    if (seg < 2) {                                       // Q or K -> fp8 scaled x8
        const float* s = seg ? s1 : s0;
        u8* d = seg ? k8 : q8;
        float4 v = ((const float4*)s)[off];
        u32 o = (u32)f2fp8(v.x * 8.f) | ((u32)f2fp8(v.y * 8.f) << 8) |
                ((u32)f2fp8(v.z * 8.f) << 16) | ((u32)f2fp8(v.w * 8.f) << 24);
        *(u32*)(d + (size_t)off * 4) = o;
    } else {                                             // V -> bf16
        float4 v = ((const float4*)s2)[off];
        u16x4 o = { f2bf(v.x), f2bf(v.y), f2bf(v.z), f2bf(v.w) };
        *(u16x4*)(vbf + (size_t)off * 4) = o;
    }
}

// ---- batched transpose+convert:
//  bz 0,1: Wq,Wk f32 [512][4096] -> fp8 (x64 scale) [4096][512]
//  bz 2:   Wv f32 [512][4096] -> bf16 [4096][512]
//  bz 3:   Wo f32 [4096][512] -> bf16 [512][4096] (grid roles swapped) ----
__global__ void k_tcvt4(const float* __restrict__ s0, const float* __restrict__ s1,
                        const float* __restrict__ s2, const float* __restrict__ s3,
                        u8* __restrict__ w8q, u8* __restrict__ w8k,
                        u16* __restrict__ wvT, u16* __restrict__ dWoT) {
    __shared__ float t[32][33];
    int bz = blockIdx.z;
    const float* s; int R, C, bx, by;
    if (bz < 3) {
        s = (bz == 0) ? s0 : (bz == 1) ? s1 : s2;
        R = 512; C = 4096;
        bx = blockIdx.x; by = blockIdx.y;                // bx<128, by<16
    } else {
        s = s3; R = 4096; C = 512;
        bx = blockIdx.y; by = blockIdx.x;                // bx<16, by<128
    }
    int tx = threadIdx.x, ty = threadIdx.y;
    #pragma unroll
    for (int j = ty; j < 32; j += 8)
        t[j][tx] = s[(size_t)(by * 32 + j) * C + bx * 32 + tx];
    __syncthreads();
    if (bz < 2) {
        u8* dd = bz ? w8k : w8q;
        #pragma unroll
        for (int j = ty; j < 32; j += 8)
            dd[(size_t)(bx * 32 + j) * R + by * 32 + tx] = f2fp8(t[tx][j] * 64.f);
    } else {
        u16* dd = (bz == 2) ? wvT : dWoT;
        #pragma unroll
        for (int j = ty; j < 32; j += 8)
            dd[(size_t)(bx * 32 + j) * R + by * 32 + tx] = f2bf(t[tx][j]);
    }
}

// final reduce: out = bias + sum over splitk partials   (2097152 f32 = 524288 float4)
__global__ void k_reduce(const float* __restrict__ part, const float* __restrict__ bias,
                         float* __restrict__ out, int splitk) {
    int i = blockIdx.x * 256 + threadIdx.x;          // float4 id
    float4 s = ((const float4*)bias)[i & 127];
    for (int j = 0; j < splitk; ++j) {
        float4 p = ((const float4*)part)[(size_t)j * 524288 + i];
        s.x += p.x; s.y += p.y; s.z += p.z; s.w += p.w;
    }
    ((float4*)out)[i] = s;
}

// ================= 128x128xK bf16 GEMM, B given transposed [N][K] ==================
// r7-verified structure: 4 waves (2x2), BK=64, single-buffered 32 KiB LDS, plain
// __syncthreads 2-barrier loop, 3 blocks/CU, 0-conflict XOR swizzle, width-16 loads.
// MODE 4: V projection only (v out bf16 transposed, bias0)
// MODE 2: O=(P v)/rowsum            MODE 3: split-K partials of Oattn@Wo
template<int MODE>
__global__ __launch_bounds__(256, 3) void k_gemm(
    const u16* __restrict__ Abase, const u16* __restrict__ Bbase,
    u16* __restrict__ out0, u16* __restrict__ out1, u16* __restrict__ out2,
    float* __restrict__ outf,
    const float* __restrict__ bias0, const float* __restrict__ bias1,
    const float* __restrict__ bias2,
    float* __restrict__ rsum, int bh_base, int ktiles)
{
    constexpr int LDA = (MODE == 2) ? 2048 : (MODE == 3) ? 4096 : 512;
    constexpr int LDB = (MODE == 2) ? 2048 : (MODE == 3) ? 4096 : 512;

    __shared__ u16 lsA[128][64];       // 16 KiB
    __shared__ u16 lsB[128][64];       // 16 KiB

    const int tid = threadIdx.x;
    const int bx = blockIdx.x, by = blockIdx.y, bz = blockIdx.z;

    const u16* A; const u16* Bt;
    if constexpr (MODE == 4) {
        A  = Abase + (size_t)by * 128 * 512;
        Bt = Bbase + (size_t)bx * 128 * 512;
    } else if constexpr (MODE == 2) {
        int bh = bh_base + bz;
        A  = Abase + (size_t)bz * 4194304 + (size_t)by * 128 * 2048;
        Bt = Bbase + (size_t)bh * 1048576 + (size_t)bx * 128 * 2048;
    } else {
        A  = Abase + (size_t)by * 128 * 4096 + (size_t)bz * (ktiles * 64);
        Bt = Bbase + (size_t)bx * 128 * 4096 + (size_t)bz * (ktiles * 64);
    }

    const int l  = tid & 63, w = tid >> 6;
    const int wm = (w >> 1) * 64, wn = (w & 1) * 64;         // wave tile origin
    const int lg = l >> 4, lr = l & 15;
    const int swz = (lr & 7) << 4;

    f32x4 acc[4][4];
    #pragma unroll
    for (int m = 0; m < 4; ++m)
        #pragma unroll
        for (int n = 0; n < 4; ++n)
            #pragma unroll
            for (int r = 0; r < 4; ++r) acc[m][n][r] = 0.f;

    for (int t = 0; t < ktiles; ++t) {
        const int koff = t * 64;
        #pragma unroll
        for (int i = 0; i < 4; ++i) {
            const int a   = (i * 256 + tid) * 16;            // linear byte in 16KB region
            const int row = a >> 7;                          // 0..127
            const int cb  = (a & 127) ^ ((row & 7) << 4);    // logical byte-in-row
            const u16* ga = A  + (size_t)row * LDA + koff + (cb >> 1);
            const u16* gb = Bt + (size_t)row * LDB + koff + (cb >> 1);
            lds_u32* la = (lds_u32*)((char*)&lsA[0][0] + i * 4096 + (w << 10));
            lds_u32* lb = (lds_u32*)((char*)&lsB[0][0] + i * 4096 + (w << 10));
            __builtin_amdgcn_global_load_lds((gbl_u32*)ga, la, 16, 0, 0);
            __builtin_amdgcn_global_load_lds((gbl_u32*)gb, lb, 16, 0, 0);
        }
        __syncthreads();                                     // drains vmcnt; tile resident

        #pragma unroll
        for (int ks = 0; ks < 2; ++ks) {
            s16x8 av[4], bv[4];
            #pragma unroll
            for (int m = 0; m < 4; ++m) {
                const int row = wm + m * 16 + lr;
                av[m] = *(const s16x8*)((const char*)&lsA[0][0] + row * 128 + ((ks * 64 + lg * 16) ^ swz));
            }
            #pragma unroll
            for (int n = 0; n < 4; ++n) {
                const int row = wn + n * 16 + lr;
                bv[n] = *(const s16x8*)((const char*)&lsB[0][0] + row * 128 + ((ks * 64 + lg * 16) ^ swz));
            }
            #pragma unroll
            for (int m = 0; m < 4; ++m)
                #pragma unroll
                for (int n = 0; n < 4; ++n)
                    acc[m][n] = __builtin_amdgcn_mfma_f32_16x16x32_bf16(av[m], bv[n], acc[m][n], 0, 0, 0);
        }
        __syncthreads();                                     // all reads done before next stage
    }

    // ---------------- epilogue: C/D col = lr, row = lg*4 + r  [m89 verified] ----------------
    if constexpr (MODE == 4) {                               // v -> bf16 transposed [B,H,D,S]
        #pragma unroll
        for (int m = 0; m < 4; ++m)
        #pragma unroll
        for (int n = 0; n < 4; ++n)
        #pragma unroll
        for (int r = 0; r < 4; ++r) {
            const int grow = by * 128 + wm + m * 16 + lg * 4 + r;   // b*2048+s
            const int gcol = bx * 128 + wn + n * 16 + lr;           // h*512+d
            const float v = acc[m][n][r] + bias0[gcol];
            const int bb = grow >> 11, ss = grow & 2047;
            const int hh = gcol >> 9,  dd = gcol & 511;
            out2[(((size_t)(bb * 8 + hh) * 512 + dd) << 11) + ss] = f2bf(v);
        }
    } else if constexpr (MODE == 2) {
        const int bh = bh_base + bz;
        const int bb = bh >> 3, hh = bh & 7;
        #pragma unroll
        for (int m = 0; m < 4; ++m)
        #pragma unroll
        for (int r = 0; r < 4; ++r) {
            const int grow = by * 128 + wm + m * 16 + lg * 4 + r;
            const float ri = 1.0f / rsum[bh * 2048 + grow];
            #pragma unroll
            for (int n = 0; n < 4; ++n) {
                const int gcol = bx * 128 + wn + n * 16 + lr;           // 0..511
                out0[((size_t)(bb * 2048 + grow) << 12) + hh * 512 + gcol] = f2bf(acc[m][n][r] * ri);
            }
        }
    } else {
        #pragma unroll
        for (int m = 0; m < 4; ++m)
        #pragma unroll
        for (int n = 0; n < 4; ++n)
        #pragma unroll
        for (int r = 0; r < 4; ++r) {
            const int grow = by * 128 + wm + m * 16 + lg * 4 + r;       // 0..4095
            const int gcol = bx * 128 + wn + n * 16 + lr;               // 0..511
            outf[(size_t)bz * 2097152 + (size_t)grow * 512 + gcol] = acc[m][n][r];
        }
    }
}

// ====== fp8 q/k projection: q = (8Q)@(64Wq)^T / 512 + bq -> fp8 [B,H,S,512] ======
// k_qk-proven structure: 128x128 tile, BK=128 fp8, 32 KiB LDS, 4 waves, (256,3).
// bz 0 = q (Q8,W8q,bq->qproj), bz 1 = k.  K=512 -> 4 K-tiles.
__global__ __launch_bounds__(256, 3) void k_pqk(
    const u8* __restrict__ Q8, const u8* __restrict__ K8,
    const u8* __restrict__ W8q, const u8* __restrict__ W8k,
    u8* __restrict__ qproj, u8* __restrict__ kproj,
    const float* __restrict__ bq, const float* __restrict__ bk)
{
    __shared__ u8 lsA[128][128];       // 16 KiB
    __shared__ u8 lsB[128][128];       // 16 KiB

    const int tid = threadIdx.x;
    const int bx = blockIdx.x, by = blockIdx.y, bz = blockIdx.z;

    const u8* A  = (bz ? K8 : Q8)  + (size_t)by * 128 * 512;
    const u8* Bt = (bz ? W8k : W8q) + (size_t)bx * 128 * 512;
    const float* bias = bz ? bk : bq;
    u8* outp = bz ? kproj : qproj;

    const int l  = tid & 63, w = tid >> 6;
    const int wm = (w >> 1) * 64, wn = (w & 1) * 64;
    const int lg = l >> 4, lr = l & 15;
    const int swz = (lr & 7) << 4;

    f32x4 acc[4][4];
    #pragma unroll
    for (int m = 0; m < 4; ++m)
        #pragma unroll
        for (int n = 0; n < 4; ++n)
            #pragma unroll
            for (int r = 0; r < 4; ++r) acc[m][n][r] = 0.f;

    for (int t = 0; t < 4; ++t) {
        const int koff = t * 128;
        #pragma unroll
        for (int i = 0; i < 4; ++i) {
            const int a   = (i * 256 + tid) * 16;            // linear byte in 16KB region
            const int row = a >> 7;                          // 0..127
            const int cb  = (a & 127) ^ ((row & 7) << 4);    // logical byte-in-row (=elem)
            const u8* ga = A  + (size_t)row * 512 + koff + cb;
            const u8* gb = Bt + (size_t)row * 512 + koff + cb;
            lds_u32* la = (lds_u32*)((char*)&lsA[0][0] + i * 4096 + (w << 10));
            lds_u32* lb = (lds_u32*)((char*)&lsB[0][0] + i * 4096 + (w << 10));
            __builtin_amdgcn_global_load_lds((gbl_u32*)ga, la, 16, 0, 0);
            __builtin_amdgcn_global_load_lds((gbl_u32*)gb, lb, 16, 0, 0);
        }
        __syncthreads();

        #pragma unroll
        for (int ks = 0; ks < 4; ++ks) {
            const int off = ks * 32 + lg * 8;
            const int po  = ((off & 0x70) ^ swz) | (off & 8);   // swizzle at 16B slots
            long av[4], bv[4];
            #pragma unroll
            for (int m = 0; m < 4; ++m) {
                const int row = wm + m * 16 + lr;
                av[m] = *(const long*)((const char*)&lsA[0][0] + row * 128 + po);
            }
            #pragma unroll
            for (int n = 0; n < 4; ++n) {
                const int row = wn + n * 16 + lr;
                bv[n] = *(const long*)((const char*)&lsB[0][0] + row * 128 + po);
            }
            #pragma unroll
            for (int m = 0; m < 4; ++m)
                #pragma unroll
                for (int n = 0; n < 4; ++n)
                    acc[m][n] = __builtin_amdgcn_mfma_f32_16x16x32_fp8_fp8(av[m], bv[n], acc[m][n], 0, 0, 0);
        }
        __syncthreads();
    }

    // epilogue: undo x8*x64 scaling, +bias, -> fp8
    #pragma unroll
    for (int m = 0; m < 4; ++m)
    #pragma unroll
    for (int n = 0; n < 4; ++n)
    #pragma unroll
    for (int r = 0; r < 4; ++r) {
        const int grow = by * 128 + wm + m * 16 + lg * 4 + r;   // b*2048+s
        const int gcol = bx * 128 + wn + n * 16 + lr;           // h*512+d
        const float v = acc[m][n][r] * 0.001953125f + bias[gcol];   // 1/512
        const int bb = grow >> 11, ss = grow & 2047;
        const int hh = gcol >> 9,  dd = gcol & 511;
        outp[(((size_t)(bb * 8 + hh) * 2048 + ss) << 9) + dd] = f2fp8(v);
    }
}

// ================= fp8 QK^T: P = exp(q k^T * scale), rowsum-atomic =================
__global__ __launch_bounds__(256, 3) void k_qk(
    const u8* __restrict__ qp, const u8* __restrict__ kp,
    u16* __restrict__ P, float* __restrict__ rsum, int bh_base)
{
    __shared__ u8 lsA[128][128];       // 16 KiB
    __shared__ u8 lsB[128][128];       // 16 KiB

    const int tid = threadIdx.x;
    const int bx = blockIdx.x, by = blockIdx.y, bz = blockIdx.z;
    const int bh = bh_base + bz;

    const u8* A  = qp + (size_t)bh * 1048576 + (size_t)by * 128 * 512;
    const u8* Bt = kp + (size_t)bh * 1048576 + (size_t)bx * 128 * 512;

    const int l  = tid & 63, w = tid >> 6;
    const int wm = (w >> 1) * 64, wn = (w & 1) * 64;
    const int lg = l >> 4, lr = l & 15;
    const int swz = (lr & 7) << 4;

    f32x4 acc[4][4];
    #pragma unroll
    for (int m = 0; m < 4; ++m)
        #pragma unroll
        for (int n = 0; n < 4; ++n)
            #pragma unroll
            for (int r = 0; r < 4; ++r) acc[m][n][r] = 0.f;

    for (int t = 0; t < 4; ++t) {
        const int koff = t * 128;
        #pragma unroll
        for (int i = 0; i < 4; ++i) {
            const int a   = (i * 256 + tid) * 16;            // linear byte in 16KB region
            const int row = a >> 7;                          // 0..127
            const int cb  = (a & 127) ^ ((row & 7) << 4);    // logical byte-in-row (=elem)
            const u8* ga = A  + (size_t)row * 512 + koff + cb;
            const u8* gb = Bt + (size_t)row * 512 + koff + cb;
            lds_u32* la = (lds_u32*)((char*)&lsA[0][0] + i * 4096 + (w << 10));
            lds_u32* lb = (lds_u32*)((char*)&lsB[0][0] + i * 4096 + (w << 10));
            __builtin_amdgcn_global_load_lds((gbl_u32*)ga, la, 16, 0, 0);
            __builtin_amdgcn_global_load_lds((gbl_u32*)gb, lb, 16, 0, 0);
        }
        __syncthreads();

        #pragma unroll
        for (int ks = 0; ks < 4; ++ks) {
            const int off = ks * 32 + lg * 8;
            const int po  = ((off & 0x70) ^ swz) | (off & 8);   // swizzle at 16B slots
            long av[4], bv[4];
            #pragma unroll
            for (int m = 0; m < 4; ++m) {
                const int row = wm + m * 16 + lr;
                av[m] = *(const long*)((const char*)&lsA[0][0] + row * 128 + po);
            }
            #pragma unroll
            for (int n = 0; n < 4; ++n) {
                const int row = wn + n * 16 + lr;
                bv[n] = *(const long*)((const char*)&lsB[0][0] + row * 128 + po);
            }
            #pragma unroll
            for (int m = 0; m < 4; ++m)
                #pragma unroll
                for (int n = 0; n < 4; ++n)
                    acc[m][n] = __builtin_amdgcn_mfma_f32_16x16x32_fp8_fp8(av[m], bv[n], acc[m][n], 0, 0, 0);
        }
        __syncthreads();
    }

    // epilogue: P = exp(acc*scale) bf16 + fused rowsum
    u16* Pp = P + (size_t)bz * 4194304;
    #pragma unroll
    for (int m = 0; m < 4; ++m)
    #pragma unroll
    for (int r = 0; r < 4; ++r) {
        const int grow = by * 128 + wm + m * 16 + lg * 4 + r;
        float rs = 0.f;
        #pragma unroll
        for (int n = 0; n < 4; ++n) {
            const int gcol = bx * 128 + wn + n * 16 + lr;
            float p = __expf(acc[m][n][r] * 0.04419417382415922f);  // 1/sqrt(512)
            rs += p;
            Pp[((size_t)grow << 11) + gcol] = f2bf(p);
        }
        #pragma unroll
        for (int o = 1; o < 16; o <<= 1) rs += __shfl_xor(rs, o, 64);
        if (lr == 0) atomicAdd(&rsum[bh * 2048 + grow], rs);
    }
}

extern "C" void kernel_launch(void* const* d_in, const int* in_sizes, int n_in,
                              void* d_out, int out_size, void* d_ws, size_t ws_size,
                              hipStream_t stream) {
    const float* Q  = (const float*)d_in[0];
    const float* K  = (const float*)d_in[1];
    const float* V  = (const float*)d_in[2];
    const float* bq = (const float*)d_in[4];
    const float* bk = (const float*)d_in[6];
    const float* bv = (const float*)d_in[8];
    const float* bo = (const float*)d_in[10];
    const float* Wq = (const float*)d_in[3];
    const float* Wk = (const float*)d_in[5];
    const float* Wv = (const float*)d_in[7];
    const float* Wo = (const float*)d_in[9];
    float* out = (float*)d_out;

    char* ws = (char*)d_ws;
    u8*    Q8    = (u8*)   (ws + 0);            // [4096][512] fp8 (x8)   [reused Q slot]
    u8*    K8    = (u8*)   (ws + 4194304);      // [4096][512] fp8 (x8)   [reused K slot]
    u16*   Vbf   = (u16*)  (ws + 8388608);      // [4096][512] bf16       [V slot]
    u8*    W8q   = (u8*)   (ws + 12582912);     // Wq^T fp8 (x64)         [reused Wt slot0]
    u8*    W8k   = (u8*)   (ws + 16777216);     // Wk^T fp8 (x64)         [reused Wt slot1]
    u16*   WvT   = (u16*)  (ws + 20971520);     // Wv^T bf16              [Wt slot2]
    u16*   WoT   = (u16*)  (ws + 25165824);     // Wo^T [512][4096] bf16
    float* rsum  = (float*)(ws + 29360128);     // [16][2048]
    u8*    qproj = (u8*)   (ws + 29491200);     // [B,H,S,512] fp8
    u8*    kproj = (u8*)   (ws + 63045632);     // [B,H,S,512] fp8
    u16*   vT    = (u16*)  (ws + 96600064);     // [B,H,512,S] bf16
    u16*   Oattn = (u16*)  (ws + 130154496);    // [B*S][4096] bf16
    u16*   P     = (u16*)  (ws + 163708928);    // chunked [ch][2048][2048] bf16
    float* part  = (float*)(ws + 163708928);    // reused after attn: [splitk][4096][512] f32

    size_t avail = (ws_size > (size_t)163708928) ? ws_size - (size_t)163708928 : 0;
    int hp = (int)(avail / 8388608);
    if (hp < 1) hp = 1;
    if (hp > 8) hp = 8;      // L3-block: attention working set ~170 MB < 256 MB L3
    int splitk = (hp >= 4) ? 4 : (hp >= 2) ? 2 : 1;      // 4 = 2 blocks/CU, 34 MB partials

    // input converts (fused; cvt3 also zeroes rsum)
    k_cvt3<<<6144, 256, 0, stream>>>(Q, K, V, Q8, K8, Vbf, rsum);
    dim3 tb(32, 8);
    k_tcvt4<<<dim3(128, 16, 4), tb, 0, stream>>>(Wq, Wk, Wv, Wo, W8q, W8k, WvT, WoT);

    // projections: q,k via fp8 GEMM (scales 8*64=512 undone in epilogue); v via bf16
    k_pqk<<<dim3(32, 32, 2), 256, 0, stream>>>(Q8, K8, W8q, W8k, qproj, kproj, bq, bk);
    k_gemm<4><<<dim3(32, 32), 256, 0, stream>>>(Vbf, WvT, nullptr, nullptr, vT, nullptr,
                                                bv, nullptr, nullptr, nullptr, 0, 8);

    // attention: P = exp(qk^T*scale) via fp8 MFMA with fused row-sums; O = P v / rowsum
    for (int h0 = 0; h0 < 16; h0 += hp) {
        int ch = (16 - h0 < hp) ? (16 - h0) : hp;
        k_qk<<<dim3(16, 16, ch), 256, 0, stream>>>(qproj, kproj, P, rsum, h0);
        k_gemm<2><<<dim3(4, 16, ch), 256, 0, stream>>>(P, vT, Oattn, nullptr, nullptr,
                                                       nullptr, nullptr, nullptr, nullptr,
                                                       rsum, h0, 32);
    }

    // final projection: split-K partials + reduce(+bias) -> f32 out
    k_gemm<3><<<dim3(4, 32, splitk), 256, 0, stream>>>(Oattn, WoT, nullptr, nullptr, nullptr,
                                                       part, nullptr, nullptr, nullptr,
                                                       nullptr, 0, 64 / splitk);
    k_reduce<<<2048, 256, 0, stream>>>(part, bo, out, splitk);
}